// Round 4
// baseline (28586.911 us; speedup 1.0000x reference)
//
#include <hip/hip_runtime.h>
#include <math.h>

#define Bsz 512
#define HID 196
#define REC 488
#define NC  35
#define TT  120
#define G3  1464
#define NSLOT 123          // 4-deep pipeline: s in [0,123)

#define KT   8
#define NCH  61            // 488 = 61*8
#define NB   61            // blocks per GEMM stage (8 cols x 3 gates each)
#define CELLB 32           // cell blocks (16 batch items each)
#define NGRID (3*NB + CELLB)   // 215 blocks, 512 thr: 1 block/CU, 8 waves/CU
#define WSL  (NCH*KT*24)   // 11712 floats = 46.8 KB per-block weight slice

// s_getreg immediate: id | (offset<<6) | ((size-1)<<11); HW_REG_XCC_ID id=20
#define HWREG_XCC_ID (20 | (0 << 6) | (31 << 11))

// LDS: only the cell blocks use it (GEMM weights ride the scalar pipe).
struct CellSmem { float xs[16][492]; float hs[16][36]; float rh[16][36]; };

__device__ __forceinline__ float sigmoidf_(float x) { return 1.0f / (1.0f + __expf(-x)); }

// ---- legacy full-fence grid barrier (used ONCE at init) ----
__device__ __forceinline__ void gbar(int* bar, int target) {
  __syncthreads();
  if (threadIdx.x == 0) {
    __builtin_amdgcn_fence(__ATOMIC_RELEASE, "agent");
    __hip_atomic_fetch_add(bar, 1, __ATOMIC_RELAXED, __HIP_MEMORY_SCOPE_AGENT);
    while (__hip_atomic_load(bar, __ATOMIC_RELAXED, __HIP_MEMORY_SCOPE_AGENT) < target)
      __builtin_amdgcn_s_sleep(2);
    __builtin_amdgcn_fence(__ATOMIC_ACQUIRE, "agent");
  }
  __syncthreads();
}

// ---- per-slot barrier: tree atomics + leader-only (per-XCD) release ----
// bar[0]            : root (one inc per XCD per slot)
// bar[32*(1+x)]     : per-XCD arrival counter
// __syncthreads() drains vmcnt -> this block's stores are in its XCD L2.
// The LAST arriver on each XCD flushes that L2 (buffer_wbl2 via release
// fence) and bumps the root: 8 wbl2 walks/slot instead of 215.
// Acquire (buffer_inv: own L1 + local L2) stays per-block -- required for
// L1 correctness; all dirty lines are already in L3 when root fires.
__device__ __forceinline__ void gbar2(int* bar, int xcd, int cntx, int nx, int s) {
  __syncthreads();
  if (threadIdx.x == 0) {
    int* bar1 = bar + 32*(1 + xcd);
    int old = __hip_atomic_fetch_add(bar1, 1, __ATOMIC_RELAXED, __HIP_MEMORY_SCOPE_AGENT);
    if (old == cntx*(s+1) - 1) {       // leader: last arriver on this XCD
      __builtin_amdgcn_fence(__ATOMIC_RELEASE, "agent");   // waitcnt + buffer_wbl2
      __hip_atomic_fetch_add(bar, 1, __ATOMIC_RELAXED, __HIP_MEMORY_SCOPE_AGENT);
    }
    while (__hip_atomic_load(bar, __ATOMIC_RELAXED, __HIP_MEMORY_SCOPE_AGENT) < nx*(s+1))
      __builtin_amdgcn_s_sleep(2);
    __builtin_amdgcn_fence(__ATOMIC_ACQUIRE, "agent");     // buffer_inv (L1+L2)
  }
  __syncthreads();
}

// ---- prologue: z = bn(X @ W.T + bias, g, beta) ----
__global__ void dense_bn_kernel(const float* __restrict__ X, const float* __restrict__ W,
                                const float* __restrict__ bias, const float* __restrict__ g,
                                const float* __restrict__ beta, float* __restrict__ Y) {
  __shared__ float xs[HID];
  int b = blockIdx.x;
  for (int k = threadIdx.x; k < HID; k += blockDim.x) xs[k] = X[(size_t)b*HID + k];
  __syncthreads();
  int j = threadIdx.x;
  if (j < HID) {
    const float4* wr = (const float4*)(W + (size_t)j*HID);
    float acc = 0.f;
    #pragma unroll 7
    for (int k4 = 0; k4 < HID/4; ++k4) {
      float4 w4 = wr[k4];
      acc += xs[4*k4+0]*w4.x + xs[4*k4+1]*w4.y + xs[4*k4+2]*w4.z + xs[4*k4+3]*w4.w;
    }
    float v = (acc + bias[j]) * 0.9995003746f;   // 1/sqrt(1+1e-3)
    Y[(size_t)b*HID + j] = g[j]*v + beta[j];
  }
}

// ---- prologue: xg0T[c][b] = (z @ Wih0.T + bih0)^T  (constant over T) ----
__global__ __launch_bounds__(256)
void xg0v2_kernel(const float* __restrict__ Z, const float* __restrict__ Wih,
                  const float* __restrict__ bih, float* __restrict__ XGT) {
  __shared__ float zs[HID*4];
  int b0 = blockIdx.x << 2;
  for (int idx = threadIdx.x; idx < HID*4; idx += 256) {
    int k = idx >> 2, i = idx & 3;
    zs[idx] = Z[(size_t)(b0+i)*HID + k];
  }
  __syncthreads();
  for (int c = threadIdx.x; c < G3; c += 256) {
    const float4* wr = (const float4*)(Wih + (size_t)c*HID);
    float a0=0.f,a1=0.f,a2=0.f,a3=0.f;
    for (int k4 = 0; k4 < HID/4; ++k4) {
      float4 w = wr[k4];
      const float* zp = zs + (k4<<4);
      a0=fmaf(w.x,zp[0],a0);  a1=fmaf(w.x,zp[1],a1);  a2=fmaf(w.x,zp[2],a2);  a3=fmaf(w.x,zp[3],a3);
      a0=fmaf(w.y,zp[4],a0);  a1=fmaf(w.y,zp[5],a1);  a2=fmaf(w.y,zp[6],a2);  a3=fmaf(w.y,zp[7],a3);
      a0=fmaf(w.z,zp[8],a0);  a1=fmaf(w.z,zp[9],a1);  a2=fmaf(w.z,zp[10],a2); a3=fmaf(w.z,zp[11],a3);
      a0=fmaf(w.w,zp[12],a0); a1=fmaf(w.w,zp[13],a1); a2=fmaf(w.w,zp[14],a2); a3=fmaf(w.w,zp[15],a3);
    }
    float bb = bih[c];
    XGT[(size_t)c*Bsz + b0+0] = a0 + bb;
    XGT[(size_t)c*Bsz + b0+1] = a1 + bb;
    XGT[(size_t)c*Bsz + b0+2] = a2 + bb;
    XGT[(size_t)c*Bsz + b0+3] = a3 + bb;
  }
}

// ---- prologue: per-block contiguous weight slices ----
// Wt2[(stage*NB + j)*WSL + ck*192 + k*24 + (g*8+cl)] = Wsrc[(g*REC + j*8 + cl)*REC + ck*8 + k]
__global__ __launch_bounds__(256)
void wtrans_kernel(const float* __restrict__ Whh0, const float* __restrict__ Wih1,
                   const float* __restrict__ Whh1, float* __restrict__ Wt2) {
  int blk = blockIdx.x;                  // 3*61
  int stage = blk / NB, j = blk - stage*NB;
  const float* Wsrc = (stage==0) ? Whh0 : (stage==1) ? Wih1 : Whh1;
  float* dst = Wt2 + (size_t)blk*WSL;
  for (int idx = threadIdx.x; idx < WSL; idx += 256) {
    int ck = idx / 192, rem = idx - ck*192;
    int k = rem / 24, r = rem - k*24;
    int g = r >> 3, cl = r & 7;
    dst[idx] = Wsrc[(size_t)(g*REC + j*8 + cl)*REC + ck*8 + k];
  }
}

// ---- acc[24] += AT[:,b] @ W-slice (24 colgates), K=488 ----
// AT layout [k][512]: per-k A-loads wave-coalesced.
// DEPTH-2 prefetch via 3-buffer rotation (PLAIN loads -> scheduler can
// pipeline with counted vmcnt; no per-chunk vmcnt(0), no av=nv copies).
// Issue->consume distance = 2 fm-groups (~1536 wall cycles at 2 waves/SIMD),
// which covers the per-slot L2-cold L3 hit (~600-900 cy).
// W read via BLOCK-UNIFORM addresses from global -> compiler emits s_load.
__device__ __forceinline__ void gemm24s(const float* __restrict__ AT, int b,
                                        const float* __restrict__ wp,
                                        float (&acc)[24])
{
  const float* base = AT + b;
  float bufA[KT], bufB[KT], bufC[KT];

  auto pf = [&](float (&buf)[KT], int c) {
    const float* src = base + (size_t)c*KT*Bsz;
    #pragma unroll
    for (int k = 0; k < KT; ++k) buf[k] = src[(size_t)k*Bsz];
  };
  auto fm = [&](const float (&buf)[KT], int c) {
    const float* w = wp + c*192;         // block-uniform -> scalar loads
    #pragma unroll
    for (int k = 0; k < KT; ++k) {
      float a = buf[k];
      #pragma unroll
      for (int r = 0; r < 24; ++r)
        acc[r] = fmaf(a, w[k*24 + r], acc[r]);
    }
  };

  pf(bufA, 0);
  pf(bufB, 1);
  // 20 iterations cover chunks 0..59; chunk 60 finishes after the loop.
  for (int ck = 0; ck < NCH-1; ck += 3) {
    pf(bufC, ck+2);
    fm(bufA, ck);
    pf(bufA, (ck+3 < NCH) ? ck+3 : NCH-1);   // clamp: harmless in-bounds dup
    fm(bufB, ck+1);
    pf(bufB, (ck+4 < NCH) ? ck+4 : NCH-1);
    fm(bufC, ck+2);
  }
  fm(bufA, NCH-1);                           // chunk 60
}

// ---- persistent kernel: 4-stage time pipeline, 215 blocks x 512 threads ----
// [0,61): GRU0 t=s | [61,122): GRU1 x-pass t=s-1 | [122,183): GRU1 h-pass t=s-2
// | [183,215): cell t=s-3.  Recurrent states TRANSPOSED [c][b]; hc normal.
__global__ __launch_bounds__(512)
void pers_kernel(const float* __restrict__ xg0T,
                 float* __restrict__ h0T, float* __restrict__ h1T,
                 float* __restrict__ xg1T, float* __restrict__ hc,
                 float* __restrict__ out,
                 const float* __restrict__ Wt2,
                 const float* __restrict__ bhh0,
                 const float* __restrict__ bih1, const float* __restrict__ bhh1,
                 const float* __restrict__ cWih, const float* __restrict__ cWhh,
                 const float* __restrict__ cb, int* __restrict__ bar)
{
  __shared__ CellSmem S;
  const int blk = blockIdx.x;
  const int tid = threadIdx.x;
  const int stage = (blk < NB) ? 0 : (blk < 2*NB) ? 1 : (blk < 3*NB) ? 2 : 3;
  const int l = tid & 63, w = tid >> 6;
  const float* wslice = Wt2 + (size_t)blk*WSL;   // block-uniform base

  // ---- init: census of blocks per XCD (true residency via XCC_ID) ----
  const int xcd = __builtin_amdgcn_s_getreg(HWREG_XCC_ID) & 7;
  if (tid == 0)
    __hip_atomic_fetch_add(bar + 32*(9 + xcd), 1, __ATOMIC_RELAXED, __HIP_MEMORY_SCOPE_AGENT);
  gbar(bar + 544, NGRID);              // full-fence barrier: census stable
  int cntx = 0, nx = 0;
  if (tid == 0) {
    cntx = __hip_atomic_load(bar + 32*(9 + xcd), __ATOMIC_RELAXED, __HIP_MEMORY_SCOPE_AGENT);
    #pragma unroll
    for (int x = 0; x < 8; ++x)
      nx += (__hip_atomic_load(bar + 32*(9 + x), __ATOMIC_RELAXED, __HIP_MEMORY_SCOPE_AGENT) > 0);
  }

  for (int s = 0; s < NSLOT; ++s) {
    if (stage == 0) {                    // ---------- GRU0, t = s ----------
      if (s < TT) {
        int j = blk;
        const float* hprevT = h0T + (size_t)((s+1)&1)*REC*Bsz;
        float*       hnewT  = h0T + (size_t)(s&1)*REC*Bsz;
        float acc[24] = {0};
        gemm24s(hprevT, tid, wslice, acc);
        int b = tid, c0 = j*8;
        #pragma unroll
        for (int cl = 0; cl < 8; ++cl) {
          int c = c0 + cl;
          float xrv = xg0T[(size_t)c*Bsz + b];
          float xzv = xg0T[(size_t)(REC+c)*Bsz + b];
          float xnv = xg0T[(size_t)(2*REC+c)*Bsz + b];
          float r = sigmoidf_(xrv + acc[cl]      + bhh0[c]);
          float z = sigmoidf_(xzv + acc[8+cl]    + bhh0[REC+c]);
          float n = tanhf   (xnv + r*(acc[16+cl] + bhh0[2*REC+c]));
          hnewT[(size_t)c*Bsz + b] = (1.f-z)*n + z*hprevT[(size_t)c*Bsz + b];
        }
      }
    } else if (stage == 1) {             // ---------- GRU1 x-pass, t = s-1 ----------
      if (s >= 1 && s <= TT) {
        int t1 = s - 1;
        const float* xT   = h0T  + (size_t)(t1&1)*REC*Bsz;
        float*       xgwT = xg1T + (size_t)(t1&1)*G3*Bsz;
        float acc[24] = {0};
        gemm24s(xT, tid, wslice, acc);
        int b = tid, c0 = (blk - NB)*8;
        #pragma unroll
        for (int cl = 0; cl < 8; ++cl) {
          int c = c0 + cl;
          xgwT[(size_t)c*Bsz + b]         = acc[cl];
          xgwT[(size_t)(REC+c)*Bsz + b]   = acc[8+cl];
          xgwT[(size_t)(2*REC+c)*Bsz + b] = acc[16+cl];
        }
      }
    } else if (stage == 2) {             // ---------- GRU1 h-pass, t = s-2 ----------
      if (s >= 2 && s <= TT+1) {
        int t2 = s - 2;
        const float* hprevT = h1T  + (size_t)((t2+1)&1)*REC*Bsz;
        float*       hnewT  = h1T  + (size_t)(t2&1)*REC*Bsz;
        const float* xgrT   = xg1T + (size_t)(t2&1)*G3*Bsz;
        float acc[24] = {0};
        gemm24s(hprevT, tid, wslice, acc);
        int b = tid, c0 = (blk - 2*NB)*8;
        #pragma unroll
        for (int cl = 0; cl < 8; ++cl) {
          int c = c0 + cl;
          float xrv = xgrT[(size_t)c*Bsz + b];
          float xzv = xgrT[(size_t)(REC+c)*Bsz + b];
          float xnv = xgrT[(size_t)(2*REC+c)*Bsz + b];
          float r = sigmoidf_(xrv + acc[cl]   + bih1[c]     + bhh1[c]);
          float z = sigmoidf_(xzv + acc[8+cl] + bih1[REC+c] + bhh1[REC+c]);
          float n = tanhf   (xnv + bih1[2*REC+c] + r*(acc[16+cl] + bhh1[2*REC+c]));
          hnewT[(size_t)c*Bsz + b] = (1.f-z)*n + z*hprevT[(size_t)c*Bsz + b];
        }
      }
    } else {                             // ---------- custom cell, t = s-3 ----------
      if (s >= 3) {
        int t3 = s - 3;
        int b0 = (blk - 3*NB) << 4;      // 16 items per block
        const float* xT = h1T + (size_t)(t3&1)*REC*Bsz;
        const float* hp = hc  + (size_t)((t3+1)&1)*Bsz*NC;
        float*       hn = hc  + (size_t)(t3&1)*Bsz*NC;
        // stage x rows from transposed slab: idx = [k][it], 16-lane segments
        for (int idx = tid; idx < 16*REC; idx += 512) {
          int k = idx >> 4, it = idx & 15;
          S.xs[it][k] = xT[(size_t)k*Bsz + b0 + it];
        }
        if (l < NC) {
          #pragma unroll
          for (int q = 0; q < 2; ++q) {
            int it = (w<<1) + q;
            S.hs[it][l] = hp[(size_t)(b0+it)*NC + l];
          }
        }
        __syncthreads();
        for (int q = 0; q < 2; ++q) {
          int it = (w<<1) + q;
          int b = b0 + it;
          float v = -1e30f, u = 0.f, hpc = 0.f;
          if (l < NC) {
            const float4* wr4 = (const float4*)(cWih + (size_t)l*REC);
            const float4* wz4 = (const float4*)(cWih + (size_t)(NC+l)*REC);
            const float4* wn4 = (const float4*)(cWih + (size_t)(2*NC+l)*REC);
            const float4* xs4 = (const float4*)(S.xs[it]);
            float xr=0.f, xz=0.f, xn=0.f;
            #pragma unroll 2
            for (int k4 = 0; k4 < REC/4; ++k4) {
              float4 xv = xs4[k4];
              float4 wa = wr4[k4], wb = wz4[k4], wc = wn4[k4];
              xr += wa.x*xv.x + wa.y*xv.y + wa.z*xv.z + wa.w*xv.w;
              xz += wb.x*xv.x + wb.y*xv.y + wb.z*xv.z + wb.w*xv.w;
              xn += wc.x*xv.x + wc.y*xv.y + wc.z*xv.z + wc.w*xv.w;
            }
            float hr=0.f, hz=0.f;
            for (int k = 0; k < NC; ++k) {
              float hv = S.hs[it][k];
              hr = fmaf(hv, cWhh[(size_t)l*NC + k], hr);
              hz = fmaf(hv, cWhh[(size_t)(NC+l)*NC + k], hz);
            }
            float r = sigmoidf_(xr + hr + cb[l]);
            u       = sigmoidf_(xz + hz + cb[NC+l]);
            hpc = S.hs[it][l];
            S.rh[it][l] = r * hpc;       // reference: (r*h) @ Whh_n.T
            v = xn;
          }
          __syncthreads();
          if (l < NC) {
            float hnn = 0.f;
            for (int k = 0; k < NC; ++k)
              hnn = fmaf(S.rh[it][k], cWhh[(size_t)(2*NC+l)*NC + k], hnn);
            v = v + hnn + cb[2*NC+l];
          }
          float m = v;
          #pragma unroll
          for (int o = 32; o; o >>= 1) m = fmaxf(m, __shfl_xor(m, o));
          float e = (l < NC) ? __expf(v - m) : 0.f;
          float ss = e;
          #pragma unroll
          for (int o = 32; o; o >>= 1) ss += __shfl_xor(ss, o);
          if (l < NC) {
            float h2 = (1.f - u)*(e/ss) + u*hpc;
            hn[(size_t)b*NC + l] = h2;
            out[((size_t)b*TT + t3)*NC + l] = h2;
          }
          __syncthreads();
        }
      }
    }
    gbar2(bar, xcd, cntx, nx, s);
  }
}

extern "C" void kernel_launch(void* const* d_in, const int* in_sizes, int n_in,
                              void* d_out, int out_size, void* d_ws, size_t ws_size,
                              hipStream_t stream) {
  const float* z_in  = (const float*)d_in[0];
  const float* W0    = (const float*)d_in[1];
  const float* b0    = (const float*)d_in[2];
  const float* g0    = (const float*)d_in[3];
  const float* beta0 = (const float*)d_in[4];
  const float* W1    = (const float*)d_in[5];
  const float* b1    = (const float*)d_in[6];
  const float* g1    = (const float*)d_in[7];
  const float* beta1 = (const float*)d_in[8];
  const float* Wih0  = (const float*)d_in[9];
  const float* Whh0  = (const float*)d_in[10];
  const float* bih0  = (const float*)d_in[11];
  const float* bhh0  = (const float*)d_in[12];
  const float* Wih1  = (const float*)d_in[13];
  const float* Whh1  = (const float*)d_in[14];
  const float* bih1  = (const float*)d_in[15];
  const float* bhh1  = (const float*)d_in[16];
  const float* cWih  = (const float*)d_in[17];
  const float* cWhh  = (const float*)d_in[18];
  const float* cbih  = (const float*)d_in[19];
  float* out = (float*)d_out;

  float* ws   = (float*)d_ws;
  int*   bar  = (int*)ws;                            // 1024 slots (zeroed)
  float* h0T  = ws   + 1024;                         // 2*REC*Bsz (zeroed)
  float* h1T  = h0T  + 2*(size_t)REC*Bsz;            // 2*REC*Bsz (zeroed)
  float* hcb  = h1T  + 2*(size_t)REC*Bsz;            // 2*Bsz*NC  (zeroed)
  float* xg1T = hcb  + 2*(size_t)Bsz*NC;             // 2*G3*Bsz
  float* xg0T = xg1T + 2*(size_t)G3*Bsz;             // G3*Bsz
  float* z1   = xg0T + (size_t)G3*Bsz;               // Bsz*HID
  float* z2   = z1   + (size_t)Bsz*HID;              // Bsz*HID
  float* Wt2  = z2   + (size_t)Bsz*HID;              // 3*NB*WSL = 8.6 MB

  size_t zero_floats = 1024 + 4*(size_t)REC*Bsz + 2*(size_t)Bsz*NC;
  hipMemsetAsync(ws, 0, zero_floats*sizeof(float), stream);

  dense_bn_kernel<<<Bsz, 256, 0, stream>>>(z_in, W0, b0, g0, beta0, z1);
  dense_bn_kernel<<<Bsz, 256, 0, stream>>>(z1,   W1, b1, g1, beta1, z2);
  xg0v2_kernel   <<<128, 256, 0, stream>>>(z2, Wih0, bih0, xg0T);
  wtrans_kernel  <<<3*NB, 256, 0, stream>>>(Whh0, Wih1, Whh1, Wt2);

  pers_kernel<<<NGRID, 512, 0, stream>>>(xg0T, h0T, h1T, xg1T, hcb, out,
                                         Wt2, bhh0, bih1, bhh1, cWih, cWhh, cbih, bar);
}

// Round 5
// 23023.511 us; speedup vs baseline: 1.2416x; 1.2416x over previous
//
#include <hip/hip_runtime.h>
#include <math.h>

#define Bsz 512
#define HID 196
#define REC 488
#define NC  35
#define TT  120
#define G3  1464
#define NSLOT 123          // 4-deep pipeline: s in [0,123)

#define KT   8
#define NCH  61            // 488 = 61*8
#define KSPL 31            // lo half: chunks [0,31), hi half: [31,61)
#define NB   61            // blocks per GEMM stage (8 cols x 3 gates each)
#define CELLB 16           // cell blocks (32 batch items each)
#define NGRID (3*NB + CELLB)   // 199 blocks x 1024 thr: 1 block/CU, 4 waves/SIMD
#define WSL  (NCH*KT*24)   // 11712 floats = 46.8 KB per-block weight slice

// s_getreg immediate: id | (offset<<6) | ((size-1)<<11); HW_REG_XCC_ID id=20
#define HWREG_XCC_ID (20 | (0 << 6) | (31 << 11))

// LDS: cell blocks stage 32 items; GEMM blocks use a K-split reduce buffer.
// red row stride 28 floats (112 B): 16B-aligned for b128 ops.
struct CellSmem { float xs[32][492]; float hs[32][36]; float rh[32][36]; };
union Smem { CellSmem cell; float red[512][28]; };

__device__ __forceinline__ float sigmoidf_(float x) { return 1.0f / (1.0f + __expf(-x)); }

// ---- legacy full-fence grid barrier (used ONCE at init) ----
__device__ __forceinline__ void gbar(int* bar, int target) {
  __syncthreads();
  if (threadIdx.x == 0) {
    __builtin_amdgcn_fence(__ATOMIC_RELEASE, "agent");
    __hip_atomic_fetch_add(bar, 1, __ATOMIC_RELAXED, __HIP_MEMORY_SCOPE_AGENT);
    while (__hip_atomic_load(bar, __ATOMIC_RELAXED, __HIP_MEMORY_SCOPE_AGENT) < target)
      __builtin_amdgcn_s_sleep(2);
    __builtin_amdgcn_fence(__ATOMIC_ACQUIRE, "agent");
  }
  __syncthreads();
}

// ---- per-slot barrier: tree atomics + leader-only (per-XCD) release ----
__device__ __forceinline__ void gbar2(int* bar, int xcd, int cntx, int nx, int s) {
  __syncthreads();
  if (threadIdx.x == 0) {
    int* bar1 = bar + 32*(1 + xcd);
    int old = __hip_atomic_fetch_add(bar1, 1, __ATOMIC_RELAXED, __HIP_MEMORY_SCOPE_AGENT);
    if (old == cntx*(s+1) - 1) {       // leader: last arriver on this XCD
      __builtin_amdgcn_fence(__ATOMIC_RELEASE, "agent");   // waitcnt + buffer_wbl2
      __hip_atomic_fetch_add(bar, 1, __ATOMIC_RELAXED, __HIP_MEMORY_SCOPE_AGENT);
    }
    while (__hip_atomic_load(bar, __ATOMIC_RELAXED, __HIP_MEMORY_SCOPE_AGENT) < nx*(s+1))
      __builtin_amdgcn_s_sleep(2);
    __builtin_amdgcn_fence(__ATOMIC_ACQUIRE, "agent");     // buffer_inv (L1+L2)
  }
  __syncthreads();
}

// ---- prologue: z = bn(X @ W.T + bias, g, beta) ----
__global__ void dense_bn_kernel(const float* __restrict__ X, const float* __restrict__ W,
                                const float* __restrict__ bias, const float* __restrict__ g,
                                const float* __restrict__ beta, float* __restrict__ Y) {
  __shared__ float xs[HID];
  int b = blockIdx.x;
  for (int k = threadIdx.x; k < HID; k += blockDim.x) xs[k] = X[(size_t)b*HID + k];
  __syncthreads();
  int j = threadIdx.x;
  if (j < HID) {
    const float4* wr = (const float4*)(W + (size_t)j*HID);
    float acc = 0.f;
    #pragma unroll 7
    for (int k4 = 0; k4 < HID/4; ++k4) {
      float4 w4 = wr[k4];
      acc += xs[4*k4+0]*w4.x + xs[4*k4+1]*w4.y + xs[4*k4+2]*w4.z + xs[4*k4+3]*w4.w;
    }
    float v = (acc + bias[j]) * 0.9995003746f;   // 1/sqrt(1+1e-3)
    Y[(size_t)b*HID + j] = g[j]*v + beta[j];
  }
}

// ---- prologue: xg0T[c][b] = (z @ Wih0.T + bih0)^T  (constant over T) ----
__global__ __launch_bounds__(256)
void xg0v2_kernel(const float* __restrict__ Z, const float* __restrict__ Wih,
                  const float* __restrict__ bih, float* __restrict__ XGT) {
  __shared__ float zs[HID*4];
  int b0 = blockIdx.x << 2;
  for (int idx = threadIdx.x; idx < HID*4; idx += 256) {
    int k = idx >> 2, i = idx & 3;
    zs[idx] = Z[(size_t)(b0+i)*HID + k];
  }
  __syncthreads();
  for (int c = threadIdx.x; c < G3; c += 256) {
    const float4* wr = (const float4*)(Wih + (size_t)c*HID);
    float a0=0.f,a1=0.f,a2=0.f,a3=0.f;
    for (int k4 = 0; k4 < HID/4; ++k4) {
      float4 w = wr[k4];
      const float* zp = zs + (k4<<4);
      a0=fmaf(w.x,zp[0],a0);  a1=fmaf(w.x,zp[1],a1);  a2=fmaf(w.x,zp[2],a2);  a3=fmaf(w.x,zp[3],a3);
      a0=fmaf(w.y,zp[4],a0);  a1=fmaf(w.y,zp[5],a1);  a2=fmaf(w.y,zp[6],a2);  a3=fmaf(w.y,zp[7],a3);
      a0=fmaf(w.z,zp[8],a0);  a1=fmaf(w.z,zp[9],a1);  a2=fmaf(w.z,zp[10],a2); a3=fmaf(w.z,zp[11],a3);
      a0=fmaf(w.w,zp[12],a0); a1=fmaf(w.w,zp[13],a1); a2=fmaf(w.w,zp[14],a2); a3=fmaf(w.w,zp[15],a3);
    }
    float bb = bih[c];
    XGT[(size_t)c*Bsz + b0+0] = a0 + bb;
    XGT[(size_t)c*Bsz + b0+1] = a1 + bb;
    XGT[(size_t)c*Bsz + b0+2] = a2 + bb;
    XGT[(size_t)c*Bsz + b0+3] = a3 + bb;
  }
}

// ---- prologue: per-block contiguous weight slices ----
// Wt2[(stage*NB + j)*WSL + ck*192 + k*24 + (g*8+cl)] = Wsrc[(g*REC + j*8 + cl)*REC + ck*8 + k]
__global__ __launch_bounds__(256)
void wtrans_kernel(const float* __restrict__ Whh0, const float* __restrict__ Wih1,
                   const float* __restrict__ Whh1, float* __restrict__ Wt2) {
  int blk = blockIdx.x;                  // 3*61
  int stage = blk / NB, j = blk - stage*NB;
  const float* Wsrc = (stage==0) ? Whh0 : (stage==1) ? Wih1 : Whh1;
  float* dst = Wt2 + (size_t)blk*WSL;
  for (int idx = threadIdx.x; idx < WSL; idx += 256) {
    int ck = idx / 192, rem = idx - ck*192;
    int k = rem / 24, r = rem - k*24;
    int g = r >> 3, cl = r & 7;
    dst[idx] = Wsrc[(size_t)(g*REC + j*8 + cl)*REC + ck*8 + k];
  }
}

// ---- acc[24] += AT[ck in [c0,c1) ][b] @ W-slice (24 colgates) ----
// Byte-identical structure to the proven R0/R3 depth-1 loop, with a
// wave-uniform chunk range [c0,c1) for the K-split halves.
__device__ __forceinline__ void gemm24s(const float* __restrict__ AT, int b,
                                        const float* __restrict__ wp,
                                        float (&acc)[24], int c0, int c1)
{
  float av[KT], nv[KT];
  const float* s0 = AT + (size_t)c0*KT*Bsz + b;
  #pragma unroll
  for (int k = 0; k < KT; ++k) av[k] = s0[(size_t)k*Bsz];
  for (int ck = c0; ck < c1; ++ck) {
    if (ck + 1 < c1) {
      const float* src = AT + (size_t)(ck+1)*KT*Bsz + b;
      #pragma unroll
      for (int k = 0; k < KT; ++k) nv[k] = src[(size_t)k*Bsz];
    }
    const float* w = wp + ck*192;        // wave-uniform -> scalar loads
    #pragma unroll
    for (int k = 0; k < KT; ++k) {
      float a = av[k];
      #pragma unroll
      for (int r = 0; r < 24; ++r)
        acc[r] = fmaf(a, w[k*24 + r], acc[r]);
    }
    #pragma unroll
    for (int k = 0; k < KT; ++k) av[k] = nv[k];
  }
}

// ---- persistent kernel: 4-stage time pipeline, 199 blocks x 1024 threads ----
// [0,61): GRU0 t=s | [61,122): GRU1 x-pass t=s-1 | [122,183): GRU1 h-pass t=s-2
// | [183,199): cell t=s-3 (32 items each).  States TRANSPOSED [c][b]; hc normal.
// K-SPLIT: tid=b+512*half; each half runs half the chunks (4 waves/SIMD for
// latency hiding), halves combine via LDS, lo half runs the epilogue.
__global__ __launch_bounds__(1024)
void pers_kernel(const float* __restrict__ xg0T,
                 float* __restrict__ h0T, float* __restrict__ h1T,
                 float* __restrict__ xg1T, float* __restrict__ hc,
                 float* __restrict__ out,
                 const float* __restrict__ Wt2,
                 const float* __restrict__ bhh0,
                 const float* __restrict__ bih1, const float* __restrict__ bhh1,
                 const float* __restrict__ cWih, const float* __restrict__ cWhh,
                 const float* __restrict__ cb, int* __restrict__ bar)
{
  __shared__ Smem S;
  const int blk = blockIdx.x;
  const int tid = threadIdx.x;
  const int stage = (blk < NB) ? 0 : (blk < 2*NB) ? 1 : (blk < 3*NB) ? 2 : 3;
  const int b = tid & 511;
  const int half = tid >> 9;
  const int c0 = half ? KSPL : 0, c1 = half ? NCH : KSPL;
  const int l = tid & 63, w = tid >> 6;          // cell: w 0..15
  const float* wslice = Wt2 + (size_t)blk*WSL;   // block-uniform base

  // ---- init: census of blocks per XCD (true residency via XCC_ID) ----
  const int xcd = __builtin_amdgcn_s_getreg(HWREG_XCC_ID) & 7;
  if (tid == 0)
    __hip_atomic_fetch_add(bar + 32*(9 + xcd), 1, __ATOMIC_RELAXED, __HIP_MEMORY_SCOPE_AGENT);
  gbar(bar + 544, NGRID);              // full-fence barrier: census stable
  int cntx = 0, nx = 0;
  if (tid == 0) {
    cntx = __hip_atomic_load(bar + 32*(9 + xcd), __ATOMIC_RELAXED, __HIP_MEMORY_SCOPE_AGENT);
    #pragma unroll
    for (int x = 0; x < 8; ++x)
      nx += (__hip_atomic_load(bar + 32*(9 + x), __ATOMIC_RELAXED, __HIP_MEMORY_SCOPE_AGENT) > 0);
  }

  for (int s = 0; s < NSLOT; ++s) {
    if (stage == 0) {                    // ---------- GRU0, t = s ----------
      if (s < TT) {
        int j = blk;
        const float* hprevT = h0T + (size_t)((s+1)&1)*REC*Bsz;
        float*       hnewT  = h0T + (size_t)(s&1)*REC*Bsz;
        float acc[24] = {0};
        gemm24s(hprevT, b, wslice, acc, c0, c1);
        if (half) {
          float4* dst = (float4*)S.red[b];
          #pragma unroll
          for (int q4 = 0; q4 < 6; ++q4)
            dst[q4] = make_float4(acc[4*q4], acc[4*q4+1], acc[4*q4+2], acc[4*q4+3]);
        }
        __syncthreads();
        if (!half) {
          const float4* srcr = (const float4*)S.red[b];
          #pragma unroll
          for (int q4 = 0; q4 < 6; ++q4) {
            float4 v = srcr[q4];
            acc[4*q4] += v.x; acc[4*q4+1] += v.y; acc[4*q4+2] += v.z; acc[4*q4+3] += v.w;
          }
          int c0g = j*8;
          #pragma unroll
          for (int cl = 0; cl < 8; ++cl) {
            int c = c0g + cl;
            float xrv = xg0T[(size_t)c*Bsz + b];
            float xzv = xg0T[(size_t)(REC+c)*Bsz + b];
            float xnv = xg0T[(size_t)(2*REC+c)*Bsz + b];
            float r = sigmoidf_(xrv + acc[cl]      + bhh0[c]);
            float z = sigmoidf_(xzv + acc[8+cl]    + bhh0[REC+c]);
            float n = tanhf   (xnv + r*(acc[16+cl] + bhh0[2*REC+c]));
            hnewT[(size_t)c*Bsz + b] = (1.f-z)*n + z*hprevT[(size_t)c*Bsz + b];
          }
        }
      }
    } else if (stage == 1) {             // ---------- GRU1 x-pass, t = s-1 ----------
      if (s >= 1 && s <= TT) {
        int t1 = s - 1;
        const float* xT   = h0T  + (size_t)(t1&1)*REC*Bsz;
        float*       xgwT = xg1T + (size_t)(t1&1)*G3*Bsz;
        float acc[24] = {0};
        gemm24s(xT, b, wslice, acc, c0, c1);
        if (half) {
          float4* dst = (float4*)S.red[b];
          #pragma unroll
          for (int q4 = 0; q4 < 6; ++q4)
            dst[q4] = make_float4(acc[4*q4], acc[4*q4+1], acc[4*q4+2], acc[4*q4+3]);
        }
        __syncthreads();
        if (!half) {
          const float4* srcr = (const float4*)S.red[b];
          #pragma unroll
          for (int q4 = 0; q4 < 6; ++q4) {
            float4 v = srcr[q4];
            acc[4*q4] += v.x; acc[4*q4+1] += v.y; acc[4*q4+2] += v.z; acc[4*q4+3] += v.w;
          }
          int c0g = (blk - NB)*8;
          #pragma unroll
          for (int cl = 0; cl < 8; ++cl) {
            int c = c0g + cl;
            xgwT[(size_t)c*Bsz + b]         = acc[cl];
            xgwT[(size_t)(REC+c)*Bsz + b]   = acc[8+cl];
            xgwT[(size_t)(2*REC+c)*Bsz + b] = acc[16+cl];
          }
        }
      }
    } else if (stage == 2) {             // ---------- GRU1 h-pass, t = s-2 ----------
      if (s >= 2 && s <= TT+1) {
        int t2 = s - 2;
        const float* hprevT = h1T  + (size_t)((t2+1)&1)*REC*Bsz;
        float*       hnewT  = h1T  + (size_t)(t2&1)*REC*Bsz;
        const float* xgrT   = xg1T + (size_t)(t2&1)*G3*Bsz;
        float acc[24] = {0};
        gemm24s(hprevT, b, wslice, acc, c0, c1);
        if (half) {
          float4* dst = (float4*)S.red[b];
          #pragma unroll
          for (int q4 = 0; q4 < 6; ++q4)
            dst[q4] = make_float4(acc[4*q4], acc[4*q4+1], acc[4*q4+2], acc[4*q4+3]);
        }
        __syncthreads();
        if (!half) {
          const float4* srcr = (const float4*)S.red[b];
          #pragma unroll
          for (int q4 = 0; q4 < 6; ++q4) {
            float4 v = srcr[q4];
            acc[4*q4] += v.x; acc[4*q4+1] += v.y; acc[4*q4+2] += v.z; acc[4*q4+3] += v.w;
          }
          int c0g = (blk - 2*NB)*8;
          #pragma unroll
          for (int cl = 0; cl < 8; ++cl) {
            int c = c0g + cl;
            float xrv = xgrT[(size_t)c*Bsz + b];
            float xzv = xgrT[(size_t)(REC+c)*Bsz + b];
            float xnv = xgrT[(size_t)(2*REC+c)*Bsz + b];
            float r = sigmoidf_(xrv + acc[cl]   + bih1[c]     + bhh1[c]);
            float z = sigmoidf_(xzv + acc[8+cl] + bih1[REC+c] + bhh1[REC+c]);
            float n = tanhf   (xnv + bih1[2*REC+c] + r*(acc[16+cl] + bhh1[2*REC+c]));
            hnewT[(size_t)c*Bsz + b] = (1.f-z)*n + z*hprevT[(size_t)c*Bsz + b];
          }
        }
      }
    } else {                             // ---------- custom cell, t = s-3 ----------
      if (s >= 3) {
        int t3 = s - 3;
        int b0 = (blk - 3*NB) << 5;      // 32 items per block
        const float* xT = h1T + (size_t)(t3&1)*REC*Bsz;
        const float* hp = hc  + (size_t)((t3+1)&1)*Bsz*NC;
        float*       hn = hc  + (size_t)(t3&1)*Bsz*NC;
        // stage x rows from transposed slab: idx = [k][it], 32-lane segments
        for (int idx = tid; idx < 32*REC; idx += 1024) {
          int k = idx >> 5, it = idx & 31;
          S.cell.xs[it][k] = xT[(size_t)k*Bsz + b0 + it];
        }
        if (l < NC) {
          #pragma unroll
          for (int q = 0; q < 2; ++q) {
            int it = (w<<1) + q;
            S.cell.hs[it][l] = hp[(size_t)(b0+it)*NC + l];
          }
        }
        __syncthreads();
        for (int q = 0; q < 2; ++q) {
          int it = (w<<1) + q;
          int bb = b0 + it;
          float v = -1e30f, u = 0.f, hpc = 0.f;
          if (l < NC) {
            const float4* wr4 = (const float4*)(cWih + (size_t)l*REC);
            const float4* wz4 = (const float4*)(cWih + (size_t)(NC+l)*REC);
            const float4* wn4 = (const float4*)(cWih + (size_t)(2*NC+l)*REC);
            const float4* xs4 = (const float4*)(S.cell.xs[it]);
            float xr=0.f, xz=0.f, xn=0.f;
            #pragma unroll 2
            for (int k4 = 0; k4 < REC/4; ++k4) {
              float4 xv = xs4[k4];
              float4 wa = wr4[k4], wb = wz4[k4], wc = wn4[k4];
              xr += wa.x*xv.x + wa.y*xv.y + wa.z*xv.z + wa.w*xv.w;
              xz += wb.x*xv.x + wb.y*xv.y + wb.z*xv.z + wb.w*xv.w;
              xn += wc.x*xv.x + wc.y*xv.y + wc.z*xv.z + wc.w*xv.w;
            }
            float hr=0.f, hz=0.f;
            for (int k = 0; k < NC; ++k) {
              float hv = S.cell.hs[it][k];
              hr = fmaf(hv, cWhh[(size_t)l*NC + k], hr);
              hz = fmaf(hv, cWhh[(size_t)(NC+l)*NC + k], hz);
            }
            float r = sigmoidf_(xr + hr + cb[l]);
            u       = sigmoidf_(xz + hz + cb[NC+l]);
            hpc = S.cell.hs[it][l];
            S.cell.rh[it][l] = r * hpc;  // reference: (r*h) @ Whh_n.T
            v = xn;
          }
          __syncthreads();
          if (l < NC) {
            float hnn = 0.f;
            for (int k = 0; k < NC; ++k)
              hnn = fmaf(S.cell.rh[it][k], cWhh[(size_t)(2*NC+l)*NC + k], hnn);
            v = v + hnn + cb[2*NC+l];
          }
          float m = v;
          #pragma unroll
          for (int o = 32; o; o >>= 1) m = fmaxf(m, __shfl_xor(m, o));
          float e = (l < NC) ? __expf(v - m) : 0.f;
          float ss = e;
          #pragma unroll
          for (int o = 32; o; o >>= 1) ss += __shfl_xor(ss, o);
          if (l < NC) {
            float h2 = (1.f - u)*(e/ss) + u*hpc;
            hn[(size_t)bb*NC + l] = h2;
            out[((size_t)bb*TT + t3)*NC + l] = h2;
          }
          __syncthreads();
        }
      }
    }
    gbar2(bar, xcd, cntx, nx, s);
  }
}

extern "C" void kernel_launch(void* const* d_in, const int* in_sizes, int n_in,
                              void* d_out, int out_size, void* d_ws, size_t ws_size,
                              hipStream_t stream) {
  const float* z_in  = (const float*)d_in[0];
  const float* W0    = (const float*)d_in[1];
  const float* b0    = (const float*)d_in[2];
  const float* g0    = (const float*)d_in[3];
  const float* beta0 = (const float*)d_in[4];
  const float* W1    = (const float*)d_in[5];
  const float* b1    = (const float*)d_in[6];
  const float* g1    = (const float*)d_in[7];
  const float* beta1 = (const float*)d_in[8];
  const float* Wih0  = (const float*)d_in[9];
  const float* Whh0  = (const float*)d_in[10];
  const float* bih0  = (const float*)d_in[11];
  const float* bhh0  = (const float*)d_in[12];
  const float* Wih1  = (const float*)d_in[13];
  const float* Whh1  = (const float*)d_in[14];
  const float* bih1  = (const float*)d_in[15];
  const float* bhh1  = (const float*)d_in[16];
  const float* cWih  = (const float*)d_in[17];
  const float* cWhh  = (const float*)d_in[18];
  const float* cbih  = (const float*)d_in[19];
  float* out = (float*)d_out;

  float* ws   = (float*)d_ws;
  int*   bar  = (int*)ws;                            // 1024 slots (zeroed)
  float* h0T  = ws   + 1024;                         // 2*REC*Bsz (zeroed)
  float* h1T  = h0T  + 2*(size_t)REC*Bsz;            // 2*REC*Bsz (zeroed)
  float* hcb  = h1T  + 2*(size_t)REC*Bsz;            // 2*Bsz*NC  (zeroed)
  float* xg1T = hcb  + 2*(size_t)Bsz*NC;             // 2*G3*Bsz
  float* xg0T = xg1T + 2*(size_t)G3*Bsz;             // G3*Bsz
  float* z1   = xg0T + (size_t)G3*Bsz;               // Bsz*HID
  float* z2   = z1   + (size_t)Bsz*HID;              // Bsz*HID
  float* Wt2  = z2   + (size_t)Bsz*HID;              // 3*NB*WSL = 8.6 MB

  size_t zero_floats = 1024 + 4*(size_t)REC*Bsz + 2*(size_t)Bsz*NC;
  hipMemsetAsync(ws, 0, zero_floats*sizeof(float), stream);

  dense_bn_kernel<<<Bsz, 256, 0, stream>>>(z_in, W0, b0, g0, beta0, z1);
  dense_bn_kernel<<<Bsz, 256, 0, stream>>>(z1,   W1, b1, g1, beta1, z2);
  xg0v2_kernel   <<<128, 256, 0, stream>>>(z2, Wih0, bih0, xg0T);
  wtrans_kernel  <<<3*NB, 256, 0, stream>>>(Whh0, Wih1, Whh1, Wt2);

  pers_kernel<<<NGRID, 1024, 0, stream>>>(xg0T, h0T, h1T, xg1T, hcb, out,
                                          Wt2, bhh0, bih1, bhh1, cWih, cWhh, cbih, bar);
}

// Round 6
// 12683.251 us; speedup vs baseline: 2.2539x; 1.8153x over previous
//
#include <hip/hip_runtime.h>
#include <math.h>

#define Bsz 512
#define HID 196
#define REC 488
#define NC  35
#define TT  120
#define G3  1464
#define NSLOT 123          // 4-deep pipeline: s in [0,123)

#define KT   8
#define NCH  61            // 488 = 61*8
#define NBG  122           // GEMM blocks per stage (4 cols x 3 gates each)
#define CELLB 32           // cell blocks (16 batch items each)
#define NGRID (3*NBG + CELLB)  // 398 blocks x 512 thr: 2 blocks/CU, 4 waves/SIMD
#define WSL  (NCH*KT*12)   // 5856 floats = 23.4 KB per-block weight slice

// s_getreg immediate: id | (offset<<6) | ((size-1)<<11); HW_REG_XCC_ID id=20
#define HWREG_XCC_ID (20 | (0 << 6) | (31 << 11))

// LDS: only the cell blocks use it (GEMM weights ride the scalar pipe).
struct CellSmem { float xs[16][492]; float hs[16][36]; float rh[16][36]; };

__device__ __forceinline__ float sigmoidf_(float x) { return 1.0f / (1.0f + __expf(-x)); }

// ---- legacy full-fence grid barrier (used ONCE at init) ----
__device__ __forceinline__ void gbar(int* bar, int target) {
  __syncthreads();
  if (threadIdx.x == 0) {
    __builtin_amdgcn_fence(__ATOMIC_RELEASE, "agent");
    __hip_atomic_fetch_add(bar, 1, __ATOMIC_RELAXED, __HIP_MEMORY_SCOPE_AGENT);
    while (__hip_atomic_load(bar, __ATOMIC_RELAXED, __HIP_MEMORY_SCOPE_AGENT) < target)
      __builtin_amdgcn_s_sleep(2);
    __builtin_amdgcn_fence(__ATOMIC_ACQUIRE, "agent");
  }
  __syncthreads();
}

// ---- per-slot barrier: tree atomics + leader-only (per-XCD) release ----
// bar[0]            : root (one inc per XCD per slot)
// bar[32*(1+x)]     : per-XCD arrival counter
// __syncthreads() drains vmcnt -> this block's stores are in its XCD L2.
// The LAST arriver on each XCD flushes that L2 (buffer_wbl2 via release
// fence) and bumps the root: 8 wbl2 walks/slot instead of 398.
// Acquire (buffer_inv: own L1 + local L2) stays per-block.
__device__ __forceinline__ void gbar2(int* bar, int xcd, int cntx, int nx, int s) {
  __syncthreads();
  if (threadIdx.x == 0) {
    int* bar1 = bar + 32*(1 + xcd);
    int old = __hip_atomic_fetch_add(bar1, 1, __ATOMIC_RELAXED, __HIP_MEMORY_SCOPE_AGENT);
    if (old == cntx*(s+1) - 1) {       // leader: last arriver on this XCD
      __builtin_amdgcn_fence(__ATOMIC_RELEASE, "agent");   // waitcnt + buffer_wbl2
      __hip_atomic_fetch_add(bar, 1, __ATOMIC_RELAXED, __HIP_MEMORY_SCOPE_AGENT);
    }
    while (__hip_atomic_load(bar, __ATOMIC_RELAXED, __HIP_MEMORY_SCOPE_AGENT) < nx*(s+1))
      __builtin_amdgcn_s_sleep(2);
    __builtin_amdgcn_fence(__ATOMIC_ACQUIRE, "agent");     // buffer_inv (L1+L2)
  }
  __syncthreads();
}

// ---- prologue: z = bn(X @ W.T + bias, g, beta) ----
__global__ void dense_bn_kernel(const float* __restrict__ X, const float* __restrict__ W,
                                const float* __restrict__ bias, const float* __restrict__ g,
                                const float* __restrict__ beta, float* __restrict__ Y) {
  __shared__ float xs[HID];
  int b = blockIdx.x;
  for (int k = threadIdx.x; k < HID; k += blockDim.x) xs[k] = X[(size_t)b*HID + k];
  __syncthreads();
  int j = threadIdx.x;
  if (j < HID) {
    const float4* wr = (const float4*)(W + (size_t)j*HID);
    float acc = 0.f;
    #pragma unroll 7
    for (int k4 = 0; k4 < HID/4; ++k4) {
      float4 w4 = wr[k4];
      acc += xs[4*k4+0]*w4.x + xs[4*k4+1]*w4.y + xs[4*k4+2]*w4.z + xs[4*k4+3]*w4.w;
    }
    float v = (acc + bias[j]) * 0.9995003746f;   // 1/sqrt(1+1e-3)
    Y[(size_t)b*HID + j] = g[j]*v + beta[j];
  }
}

// ---- prologue: xg0T[c][b] = (z @ Wih0.T + bih0)^T  (constant over T) ----
__global__ __launch_bounds__(256)
void xg0v2_kernel(const float* __restrict__ Z, const float* __restrict__ Wih,
                  const float* __restrict__ bih, float* __restrict__ XGT) {
  __shared__ float zs[HID*4];
  int b0 = blockIdx.x << 2;
  for (int idx = threadIdx.x; idx < HID*4; idx += 256) {
    int k = idx >> 2, i = idx & 3;
    zs[idx] = Z[(size_t)(b0+i)*HID + k];
  }
  __syncthreads();
  for (int c = threadIdx.x; c < G3; c += 256) {
    const float4* wr = (const float4*)(Wih + (size_t)c*HID);
    float a0=0.f,a1=0.f,a2=0.f,a3=0.f;
    for (int k4 = 0; k4 < HID/4; ++k4) {
      float4 w = wr[k4];
      const float* zp = zs + (k4<<4);
      a0=fmaf(w.x,zp[0],a0);  a1=fmaf(w.x,zp[1],a1);  a2=fmaf(w.x,zp[2],a2);  a3=fmaf(w.x,zp[3],a3);
      a0=fmaf(w.y,zp[4],a0);  a1=fmaf(w.y,zp[5],a1);  a2=fmaf(w.y,zp[6],a2);  a3=fmaf(w.y,zp[7],a3);
      a0=fmaf(w.z,zp[8],a0);  a1=fmaf(w.z,zp[9],a1);  a2=fmaf(w.z,zp[10],a2); a3=fmaf(w.z,zp[11],a3);
      a0=fmaf(w.w,zp[12],a0); a1=fmaf(w.w,zp[13],a1); a2=fmaf(w.w,zp[14],a2); a3=fmaf(w.w,zp[15],a3);
    }
    float bb = bih[c];
    XGT[(size_t)c*Bsz + b0+0] = a0 + bb;
    XGT[(size_t)c*Bsz + b0+1] = a1 + bb;
    XGT[(size_t)c*Bsz + b0+2] = a2 + bb;
    XGT[(size_t)c*Bsz + b0+3] = a3 + bb;
  }
}

// ---- prologue: per-block contiguous weight slices (4 cols x 3 gates) ----
// Wt2[(stage*NBG + j)*WSL + ck*96 + k*12 + (g*4+cl)]
//   = Wsrc[(g*REC + j*4 + cl)*REC + ck*8 + k]
__global__ __launch_bounds__(256)
void wtrans_kernel(const float* __restrict__ Whh0, const float* __restrict__ Wih1,
                   const float* __restrict__ Whh1, float* __restrict__ Wt2) {
  int blk = blockIdx.x;                  // 3*122
  int stage = blk / NBG, j = blk - stage*NBG;
  const float* Wsrc = (stage==0) ? Whh0 : (stage==1) ? Wih1 : Whh1;
  float* dst = Wt2 + (size_t)blk*WSL;
  for (int idx = threadIdx.x; idx < WSL; idx += 256) {
    int ck = idx / 96, rem = idx - ck*96;
    int k = rem / 12, r = rem - k*12;
    int g = r >> 2, cl = r & 3;
    dst[idx] = Wsrc[(size_t)(g*REC + j*4 + cl)*REC + ck*8 + k];
  }
}

// ---- acc[12] += AT[:,b] @ W-slice (12 colgates), K=488 ----
// Byte-identical structure to the proven R0/R3 depth-1 loop, with the
// per-block output width halved (4 cols x 3 gates): ~60 live VGPRs, so
// two 512-thread blocks co-reside per CU (4 waves/SIMD) without spills.
// W read via BLOCK-UNIFORM addresses from global -> compiler emits s_load.
__device__ __forceinline__ void gemm12s(const float* __restrict__ AT, int b,
                                        const float* __restrict__ wp,
                                        float (&acc)[12])
{
  float av[KT], nv[KT];
  #pragma unroll
  for (int k = 0; k < KT; ++k) av[k] = AT[(size_t)k*Bsz + b];
  for (int ck = 0; ck < NCH; ++ck) {
    if (ck + 1 < NCH) {
      const float* src = AT + (size_t)(ck+1)*KT*Bsz + b;
      #pragma unroll
      for (int k = 0; k < KT; ++k) nv[k] = src[(size_t)k*Bsz];
    }
    const float* w = wp + ck*96;         // block-uniform -> scalar loads
    #pragma unroll
    for (int k = 0; k < KT; ++k) {
      float a = av[k];
      #pragma unroll
      for (int r = 0; r < 12; ++r)
        acc[r] = fmaf(a, w[k*12 + r], acc[r]);
    }
    #pragma unroll
    for (int k = 0; k < KT; ++k) av[k] = nv[k];
  }
}

// ---- persistent kernel: 4-stage time pipeline, 398 blocks x 512 threads ----
// [0,122): GRU0 t=s | [122,244): GRU1 x-pass t=s-1 | [244,366): GRU1 h-pass
// t=s-2 | [366,398): cell t=s-3.  States TRANSPOSED [c][b]; hc normal.
__global__ __launch_bounds__(512, 4)
void pers_kernel(const float* __restrict__ xg0T,
                 float* __restrict__ h0T, float* __restrict__ h1T,
                 float* __restrict__ xg1T, float* __restrict__ hc,
                 float* __restrict__ out,
                 const float* __restrict__ Wt2,
                 const float* __restrict__ bhh0,
                 const float* __restrict__ bih1, const float* __restrict__ bhh1,
                 const float* __restrict__ cWih, const float* __restrict__ cWhh,
                 const float* __restrict__ cb, int* __restrict__ bar)
{
  __shared__ CellSmem S;
  const int blk = blockIdx.x;
  const int tid = threadIdx.x;
  const int stage = (blk < NBG) ? 0 : (blk < 2*NBG) ? 1 : (blk < 3*NBG) ? 2 : 3;
  const int l = tid & 63, w = tid >> 6;
  const float* wslice = Wt2 + (size_t)blk*WSL;   // block-uniform base

  // ---- init: census of blocks per XCD (true residency via XCC_ID) ----
  const int xcd = __builtin_amdgcn_s_getreg(HWREG_XCC_ID) & 7;
  if (tid == 0)
    __hip_atomic_fetch_add(bar + 32*(9 + xcd), 1, __ATOMIC_RELAXED, __HIP_MEMORY_SCOPE_AGENT);
  gbar(bar + 544, NGRID);              // full-fence barrier: census stable
  int cntx = 0, nx = 0;
  if (tid == 0) {
    cntx = __hip_atomic_load(bar + 32*(9 + xcd), __ATOMIC_RELAXED, __HIP_MEMORY_SCOPE_AGENT);
    #pragma unroll
    for (int x = 0; x < 8; ++x)
      nx += (__hip_atomic_load(bar + 32*(9 + x), __ATOMIC_RELAXED, __HIP_MEMORY_SCOPE_AGENT) > 0);
  }

  for (int s = 0; s < NSLOT; ++s) {
    if (stage == 0) {                    // ---------- GRU0, t = s ----------
      if (s < TT) {
        int j = blk;
        const float* hprevT = h0T + (size_t)((s+1)&1)*REC*Bsz;
        float*       hnewT  = h0T + (size_t)(s&1)*REC*Bsz;
        float acc[12] = {0};
        gemm12s(hprevT, tid, wslice, acc);
        int b = tid, c0 = j*4;
        #pragma unroll
        for (int cl = 0; cl < 4; ++cl) {
          int c = c0 + cl;
          float xrv = xg0T[(size_t)c*Bsz + b];
          float xzv = xg0T[(size_t)(REC+c)*Bsz + b];
          float xnv = xg0T[(size_t)(2*REC+c)*Bsz + b];
          float r = sigmoidf_(xrv + acc[cl]     + bhh0[c]);
          float z = sigmoidf_(xzv + acc[4+cl]   + bhh0[REC+c]);
          float n = tanhf   (xnv + r*(acc[8+cl] + bhh0[2*REC+c]));
          hnewT[(size_t)c*Bsz + b] = (1.f-z)*n + z*hprevT[(size_t)c*Bsz + b];
        }
      }
    } else if (stage == 1) {             // ---------- GRU1 x-pass, t = s-1 ----------
      if (s >= 1 && s <= TT) {
        int t1 = s - 1;
        const float* xT   = h0T  + (size_t)(t1&1)*REC*Bsz;
        float*       xgwT = xg1T + (size_t)(t1&1)*G3*Bsz;
        float acc[12] = {0};
        gemm12s(xT, tid, wslice, acc);
        int b = tid, c0 = (blk - NBG)*4;
        #pragma unroll
        for (int cl = 0; cl < 4; ++cl) {
          int c = c0 + cl;
          xgwT[(size_t)c*Bsz + b]         = acc[cl];
          xgwT[(size_t)(REC+c)*Bsz + b]   = acc[4+cl];
          xgwT[(size_t)(2*REC+c)*Bsz + b] = acc[8+cl];
        }
      }
    } else if (stage == 2) {             // ---------- GRU1 h-pass, t = s-2 ----------
      if (s >= 2 && s <= TT+1) {
        int t2 = s - 2;
        const float* hprevT = h1T  + (size_t)((t2+1)&1)*REC*Bsz;
        float*       hnewT  = h1T  + (size_t)(t2&1)*REC*Bsz;
        const float* xgrT   = xg1T + (size_t)(t2&1)*G3*Bsz;
        float acc[12] = {0};
        gemm12s(hprevT, tid, wslice, acc);
        int b = tid, c0 = (blk - 2*NBG)*4;
        #pragma unroll
        for (int cl = 0; cl < 4; ++cl) {
          int c = c0 + cl;
          float xrv = xgrT[(size_t)c*Bsz + b];
          float xzv = xgrT[(size_t)(REC+c)*Bsz + b];
          float xnv = xgrT[(size_t)(2*REC+c)*Bsz + b];
          float r = sigmoidf_(xrv + acc[cl]   + bih1[c]     + bhh1[c]);
          float z = sigmoidf_(xzv + acc[4+cl] + bih1[REC+c] + bhh1[REC+c]);
          float n = tanhf   (xnv + bih1[2*REC+c] + r*(acc[8+cl] + bhh1[2*REC+c]));
          hnewT[(size_t)c*Bsz + b] = (1.f-z)*n + z*hprevT[(size_t)c*Bsz + b];
        }
      }
    } else {                             // ---------- custom cell, t = s-3 ----------
      if (s >= 3) {
        int t3 = s - 3;
        int b0 = (blk - 3*NBG) << 4;     // 16 items per block
        const float* xT = h1T + (size_t)(t3&1)*REC*Bsz;
        const float* hp = hc  + (size_t)((t3+1)&1)*Bsz*NC;
        float*       hn = hc  + (size_t)(t3&1)*Bsz*NC;
        // stage x rows from transposed slab: idx = [k][it], 16-lane segments
        for (int idx = tid; idx < 16*REC; idx += 512) {
          int k = idx >> 4, it = idx & 15;
          S.xs[it][k] = xT[(size_t)k*Bsz + b0 + it];
        }
        if (l < NC) {
          #pragma unroll
          for (int q = 0; q < 2; ++q) {
            int it = (w<<1) + q;
            S.hs[it][l] = hp[(size_t)(b0+it)*NC + l];
          }
        }
        __syncthreads();
        for (int q = 0; q < 2; ++q) {
          int it = (w<<1) + q;
          int b = b0 + it;
          float v = -1e30f, u = 0.f, hpc = 0.f;
          if (l < NC) {
            const float4* wr4 = (const float4*)(cWih + (size_t)l*REC);
            const float4* wz4 = (const float4*)(cWih + (size_t)(NC+l)*REC);
            const float4* wn4 = (const float4*)(cWih + (size_t)(2*NC+l)*REC);
            const float4* xs4 = (const float4*)(S.xs[it]);
            float xr=0.f, xz=0.f, xn=0.f;
            #pragma unroll 2
            for (int k4 = 0; k4 < REC/4; ++k4) {
              float4 xv = xs4[k4];
              float4 wa = wr4[k4], wb = wz4[k4], wc = wn4[k4];
              xr += wa.x*xv.x + wa.y*xv.y + wa.z*xv.z + wa.w*xv.w;
              xz += wb.x*xv.x + wb.y*xv.y + wb.z*xv.z + wb.w*xv.w;
              xn += wc.x*xv.x + wc.y*xv.y + wc.z*xv.z + wc.w*xv.w;
            }
            float hr=0.f, hz=0.f;
            for (int k = 0; k < NC; ++k) {
              float hv = S.hs[it][k];
              hr = fmaf(hv, cWhh[(size_t)l*NC + k], hr);
              hz = fmaf(hv, cWhh[(size_t)(NC+l)*NC + k], hz);
            }
            float r = sigmoidf_(xr + hr + cb[l]);
            u       = sigmoidf_(xz + hz + cb[NC+l]);
            hpc = S.hs[it][l];
            S.rh[it][l] = r * hpc;       // reference: (r*h) @ Whh_n.T
            v = xn;
          }
          __syncthreads();
          if (l < NC) {
            float hnn = 0.f;
            for (int k = 0; k < NC; ++k)
              hnn = fmaf(S.rh[it][k], cWhh[(size_t)(2*NC+l)*NC + k], hnn);
            v = v + hnn + cb[2*NC+l];
          }
          float m = v;
          #pragma unroll
          for (int o = 32; o; o >>= 1) m = fmaxf(m, __shfl_xor(m, o));
          float e = (l < NC) ? __expf(v - m) : 0.f;
          float ss = e;
          #pragma unroll
          for (int o = 32; o; o >>= 1) ss += __shfl_xor(ss, o);
          if (l < NC) {
            float h2 = (1.f - u)*(e/ss) + u*hpc;
            hn[(size_t)b*NC + l] = h2;
            out[((size_t)b*TT + t3)*NC + l] = h2;
          }
          __syncthreads();
        }
      }
    }
    gbar2(bar, xcd, cntx, nx, s);
  }
}

extern "C" void kernel_launch(void* const* d_in, const int* in_sizes, int n_in,
                              void* d_out, int out_size, void* d_ws, size_t ws_size,
                              hipStream_t stream) {
  const float* z_in  = (const float*)d_in[0];
  const float* W0    = (const float*)d_in[1];
  const float* b0    = (const float*)d_in[2];
  const float* g0    = (const float*)d_in[3];
  const float* beta0 = (const float*)d_in[4];
  const float* W1    = (const float*)d_in[5];
  const float* b1    = (const float*)d_in[6];
  const float* g1    = (const float*)d_in[7];
  const float* beta1 = (const float*)d_in[8];
  const float* Wih0  = (const float*)d_in[9];
  const float* Whh0  = (const float*)d_in[10];
  const float* bih0  = (const float*)d_in[11];
  const float* bhh0  = (const float*)d_in[12];
  const float* Wih1  = (const float*)d_in[13];
  const float* Whh1  = (const float*)d_in[14];
  const float* bih1  = (const float*)d_in[15];
  const float* bhh1  = (const float*)d_in[16];
  const float* cWih  = (const float*)d_in[17];
  const float* cWhh  = (const float*)d_in[18];
  const float* cbih  = (const float*)d_in[19];
  float* out = (float*)d_out;

  float* ws   = (float*)d_ws;
  int*   bar  = (int*)ws;                            // 1024 slots (zeroed)
  float* h0T  = ws   + 1024;                         // 2*REC*Bsz (zeroed)
  float* h1T  = h0T  + 2*(size_t)REC*Bsz;            // 2*REC*Bsz (zeroed)
  float* hcb  = h1T  + 2*(size_t)REC*Bsz;            // 2*Bsz*NC  (zeroed)
  float* xg1T = hcb  + 2*(size_t)Bsz*NC;             // 2*G3*Bsz
  float* xg0T = xg1T + 2*(size_t)G3*Bsz;             // G3*Bsz
  float* z1   = xg0T + (size_t)G3*Bsz;               // Bsz*HID
  float* z2   = z1   + (size_t)Bsz*HID;              // Bsz*HID
  float* Wt2  = z2   + (size_t)Bsz*HID;              // 3*NBG*WSL = 8.6 MB

  size_t zero_floats = 1024 + 4*(size_t)REC*Bsz + 2*(size_t)Bsz*NC;
  hipMemsetAsync(ws, 0, zero_floats*sizeof(float), stream);

  dense_bn_kernel<<<Bsz, 256, 0, stream>>>(z_in, W0, b0, g0, beta0, z1);
  dense_bn_kernel<<<Bsz, 256, 0, stream>>>(z1,   W1, b1, g1, beta1, z2);
  xg0v2_kernel   <<<128, 256, 0, stream>>>(z2, Wih0, bih0, xg0T);
  wtrans_kernel  <<<3*NBG, 256, 0, stream>>>(Whh0, Wih1, Whh1, Wt2);

  pers_kernel<<<NGRID, 512, 0, stream>>>(xg0T, h0T, h1T, xg1T, hcb, out,
                                         Wt2, bhh0, bih1, bhh1, cWih, cWhh, cbih, bar);
}

// Round 7
// 10993.417 us; speedup vs baseline: 2.6004x; 1.1537x over previous
//
#include <hip/hip_runtime.h>
#include <math.h>

#define Bsz 512
#define HID 196
#define REC 488
#define NC  35
#define TT  120
#define G3  1464
#define NSLOT 123          // 4-deep pipeline: s in [0,123)

#define KT   8
#define NCH  61            // 488 = 61*8
#define NB   61            // blocks per GEMM stage (8 cols x 3 gates each)
#define CELLB 32           // cell blocks (16 batch items each)
#define NGRID (3*NB + CELLB)   // 215 blocks, 512 thr: 1 block/CU, 8 waves/CU
#define WSL  (NCH*KT*24)   // 11712 floats = 46.8 KB per-block weight slice

// s_getreg immediate: id | (offset<<6) | ((size-1)<<11); HW_REG_XCC_ID id=20
#define HWREG_XCC_ID (20 | (0 << 6) | (31 << 11))

// LDS: only the cell blocks use it (GEMM weights ride the scalar pipe).
struct CellSmem { float xs[16][492]; float hs[16][36]; float rh[16][36]; };

__device__ __forceinline__ float sigmoidf_(float x) { return 1.0f / (1.0f + __expf(-x)); }

// ---- legacy full-fence grid barrier (used ONCE at init) ----
__device__ __forceinline__ void gbar(int* bar, int target) {
  __syncthreads();
  if (threadIdx.x == 0) {
    __builtin_amdgcn_fence(__ATOMIC_RELEASE, "agent");
    __hip_atomic_fetch_add(bar, 1, __ATOMIC_RELAXED, __HIP_MEMORY_SCOPE_AGENT);
    while (__hip_atomic_load(bar, __ATOMIC_RELAXED, __HIP_MEMORY_SCOPE_AGENT) < target)
      __builtin_amdgcn_s_sleep(2);
    __builtin_amdgcn_fence(__ATOMIC_ACQUIRE, "agent");
  }
  __syncthreads();
}

// ---- per-slot barrier: leader-only release AND leader-only L2 invalidate ----
// bar[0]              : root (one inc per XCD per slot)
// bar[32*(1+x)]       : per-XCD arrival counter (cumulative)
// bar[32*(18+x)]      : per-XCD "L2 invalidated for slot s" flag (cumulative)
// Release side (R3-proven): last arriver per XCD = leader; only it executes
// the agent release fence (waitcnt + buffer_wbl2) -> 8 wbl2 walks/slot.
// Acquire side (NEW): after root fires, all dirty data is in L3. Stale copies
// live in each XCD L2 (killed ONCE by the leader's agent-acquire fence:
// buffer_inv sc1) and each CU L1 (killed per-block by plain buffer_inv,
// L1-only). Non-leaders wait for the leader's inv_done flag before their L1
// inv, so no read can be served from a stale L2.
__device__ __forceinline__ void gbar3(int* bar, int xcd, int cntx, int nx, int s) {
  __syncthreads();
  if (threadIdx.x == 0) {
    int* bar1 = bar + 32*(1 + xcd);
    int old = __hip_atomic_fetch_add(bar1, 1, __ATOMIC_RELAXED, __HIP_MEMORY_SCOPE_AGENT);
    const bool leader = (old == cntx*(s+1) - 1);   // last arriver on this XCD
    if (leader) {
      __builtin_amdgcn_fence(__ATOMIC_RELEASE, "agent");   // waitcnt + buffer_wbl2
      __hip_atomic_fetch_add(bar, 1, __ATOMIC_RELAXED, __HIP_MEMORY_SCOPE_AGENT);
    }
    while (__hip_atomic_load(bar, __ATOMIC_RELAXED, __HIP_MEMORY_SCOPE_AGENT) < nx*(s+1))
      __builtin_amdgcn_s_sleep(2);
    if (leader) {
      __builtin_amdgcn_fence(__ATOMIC_ACQUIRE, "agent");   // buffer_inv sc1: L1+L2
      __hip_atomic_fetch_add(bar + 32*(18 + xcd), 1, __ATOMIC_RELAXED, __HIP_MEMORY_SCOPE_AGENT);
    } else {
      while (__hip_atomic_load(bar + 32*(18 + xcd), __ATOMIC_RELAXED, __HIP_MEMORY_SCOPE_AGENT) < (s+1))
        __builtin_amdgcn_s_sleep(1);
      // L1-only invalidate (no sc1): our XCD L2 is already clean.
      asm volatile("buffer_inv\n\ts_waitcnt vmcnt(0)" ::: "memory");
    }
  }
  __syncthreads();
}

// ---- prologue: z = bn(X @ W.T + bias, g, beta) ----
__global__ void dense_bn_kernel(const float* __restrict__ X, const float* __restrict__ W,
                                const float* __restrict__ bias, const float* __restrict__ g,
                                const float* __restrict__ beta, float* __restrict__ Y) {
  __shared__ float xs[HID];
  int b = blockIdx.x;
  for (int k = threadIdx.x; k < HID; k += blockDim.x) xs[k] = X[(size_t)b*HID + k];
  __syncthreads();
  int j = threadIdx.x;
  if (j < HID) {
    const float4* wr = (const float4*)(W + (size_t)j*HID);
    float acc = 0.f;
    #pragma unroll 7
    for (int k4 = 0; k4 < HID/4; ++k4) {
      float4 w4 = wr[k4];
      acc += xs[4*k4+0]*w4.x + xs[4*k4+1]*w4.y + xs[4*k4+2]*w4.z + xs[4*k4+3]*w4.w;
    }
    float v = (acc + bias[j]) * 0.9995003746f;   // 1/sqrt(1+1e-3)
    Y[(size_t)b*HID + j] = g[j]*v + beta[j];
  }
}

// ---- prologue: xg0T[c][b] = (z @ Wih0.T + bih0)^T  (constant over T) ----
__global__ __launch_bounds__(256)
void xg0v2_kernel(const float* __restrict__ Z, const float* __restrict__ Wih,
                  const float* __restrict__ bih, float* __restrict__ XGT) {
  __shared__ float zs[HID*4];
  int b0 = blockIdx.x << 2;
  for (int idx = threadIdx.x; idx < HID*4; idx += 256) {
    int k = idx >> 2, i = idx & 3;
    zs[idx] = Z[(size_t)(b0+i)*HID + k];
  }
  __syncthreads();
  for (int c = threadIdx.x; c < G3; c += 256) {
    const float4* wr = (const float4*)(Wih + (size_t)c*HID);
    float a0=0.f,a1=0.f,a2=0.f,a3=0.f;
    for (int k4 = 0; k4 < HID/4; ++k4) {
      float4 w = wr[k4];
      const float* zp = zs + (k4<<4);
      a0=fmaf(w.x,zp[0],a0);  a1=fmaf(w.x,zp[1],a1);  a2=fmaf(w.x,zp[2],a2);  a3=fmaf(w.x,zp[3],a3);
      a0=fmaf(w.y,zp[4],a0);  a1=fmaf(w.y,zp[5],a1);  a2=fmaf(w.y,zp[6],a2);  a3=fmaf(w.y,zp[7],a3);
      a0=fmaf(w.z,zp[8],a0);  a1=fmaf(w.z,zp[9],a1);  a2=fmaf(w.z,zp[10],a2); a3=fmaf(w.z,zp[11],a3);
      a0=fmaf(w.w,zp[12],a0); a1=fmaf(w.w,zp[13],a1); a2=fmaf(w.w,zp[14],a2); a3=fmaf(w.w,zp[15],a3);
    }
    float bb = bih[c];
    XGT[(size_t)c*Bsz + b0+0] = a0 + bb;
    XGT[(size_t)c*Bsz + b0+1] = a1 + bb;
    XGT[(size_t)c*Bsz + b0+2] = a2 + bb;
    XGT[(size_t)c*Bsz + b0+3] = a3 + bb;
  }
}

// ---- prologue: per-block contiguous weight slices ----
// Wt2[(stage*NB + j)*WSL + ck*192 + k*24 + (g*8+cl)] = Wsrc[(g*REC + j*8 + cl)*REC + ck*8 + k]
__global__ __launch_bounds__(256)
void wtrans_kernel(const float* __restrict__ Whh0, const float* __restrict__ Wih1,
                   const float* __restrict__ Whh1, float* __restrict__ Wt2) {
  int blk = blockIdx.x;                  // 3*61
  int stage = blk / NB, j = blk - stage*NB;
  const float* Wsrc = (stage==0) ? Whh0 : (stage==1) ? Wih1 : Whh1;
  float* dst = Wt2 + (size_t)blk*WSL;
  for (int idx = threadIdx.x; idx < WSL; idx += 256) {
    int ck = idx / 192, rem = idx - ck*192;
    int k = rem / 24, r = rem - k*24;
    int g = r >> 3, cl = r & 7;
    dst[idx] = Wsrc[(size_t)(g*REC + j*8 + cl)*REC + ck*8 + k];
  }
}

// ---- acc[24] += AT[:,b] @ W-slice (24 colgates), K=488 ----
// AT layout [k][512]: per-k A-loads wave-coalesced; depth-1 chunk prefetch.
// W read via BLOCK-UNIFORM addresses from global -> compiler emits s_load
// (scalar cache + SGPR operand in v_fma): zero LDS traffic in the K-loop.
__device__ __forceinline__ void gemm24s(const float* __restrict__ AT, int b,
                                        const float* __restrict__ wp,
                                        float (&acc)[24])
{
  float av[KT], nv[KT];
  #pragma unroll
  for (int k = 0; k < KT; ++k) av[k] = AT[(size_t)k*Bsz + b];
  for (int ck = 0; ck < NCH; ++ck) {
    if (ck + 1 < NCH) {
      const float* src = AT + (size_t)(ck+1)*KT*Bsz + b;
      #pragma unroll
      for (int k = 0; k < KT; ++k) nv[k] = src[(size_t)k*Bsz];
    }
    const float* w = wp + ck*192;        // block-uniform -> scalar loads
    #pragma unroll
    for (int k = 0; k < KT; ++k) {
      float a = av[k];
      #pragma unroll
      for (int r = 0; r < 24; ++r)
        acc[r] = fmaf(a, w[k*24 + r], acc[r]);
    }
    #pragma unroll
    for (int k = 0; k < KT; ++k) av[k] = nv[k];
  }
}

// ---- persistent kernel: 4-stage time pipeline, 215 blocks x 512 threads ----
// [0,61): GRU0 t=s | [61,122): GRU1 x-pass t=s-1 | [122,183): GRU1 h-pass t=s-2
// | [183,215): cell t=s-3.  Recurrent states TRANSPOSED [c][b]; hc normal.
__global__ __launch_bounds__(512)
void pers_kernel(const float* __restrict__ xg0T,
                 float* __restrict__ h0T, float* __restrict__ h1T,
                 float* __restrict__ xg1T, float* __restrict__ hc,
                 float* __restrict__ out,
                 const float* __restrict__ Wt2,
                 const float* __restrict__ bhh0,
                 const float* __restrict__ bih1, const float* __restrict__ bhh1,
                 const float* __restrict__ cWih, const float* __restrict__ cWhh,
                 const float* __restrict__ cb, int* __restrict__ bar)
{
  __shared__ CellSmem S;
  const int blk = blockIdx.x;
  const int tid = threadIdx.x;
  const int stage = (blk < NB) ? 0 : (blk < 2*NB) ? 1 : (blk < 3*NB) ? 2 : 3;
  const int l = tid & 63, w = tid >> 6;
  const float* wslice = Wt2 + (size_t)blk*WSL;   // block-uniform base

  // ---- init: census of blocks per XCD (true residency via XCC_ID) ----
  const int xcd = __builtin_amdgcn_s_getreg(HWREG_XCC_ID) & 7;
  if (tid == 0)
    __hip_atomic_fetch_add(bar + 32*(9 + xcd), 1, __ATOMIC_RELAXED, __HIP_MEMORY_SCOPE_AGENT);
  gbar(bar + 544, NGRID);              // full-fence barrier: census stable
  int cntx = 0, nx = 0;
  if (tid == 0) {
    cntx = __hip_atomic_load(bar + 32*(9 + xcd), __ATOMIC_RELAXED, __HIP_MEMORY_SCOPE_AGENT);
    #pragma unroll
    for (int x = 0; x < 8; ++x)
      nx += (__hip_atomic_load(bar + 32*(9 + x), __ATOMIC_RELAXED, __HIP_MEMORY_SCOPE_AGENT) > 0);
  }

  for (int s = 0; s < NSLOT; ++s) {
    if (stage == 0) {                    // ---------- GRU0, t = s ----------
      if (s < TT) {
        int j = blk;
        const float* hprevT = h0T + (size_t)((s+1)&1)*REC*Bsz;
        float*       hnewT  = h0T + (size_t)(s&1)*REC*Bsz;
        float acc[24] = {0};
        gemm24s(hprevT, tid, wslice, acc);
        int b = tid, c0 = j*8;
        #pragma unroll
        for (int cl = 0; cl < 8; ++cl) {
          int c = c0 + cl;
          float xrv = xg0T[(size_t)c*Bsz + b];
          float xzv = xg0T[(size_t)(REC+c)*Bsz + b];
          float xnv = xg0T[(size_t)(2*REC+c)*Bsz + b];
          float r = sigmoidf_(xrv + acc[cl]      + bhh0[c]);
          float z = sigmoidf_(xzv + acc[8+cl]    + bhh0[REC+c]);
          float n = tanhf   (xnv + r*(acc[16+cl] + bhh0[2*REC+c]));
          hnewT[(size_t)c*Bsz + b] = (1.f-z)*n + z*hprevT[(size_t)c*Bsz + b];
        }
      }
    } else if (stage == 1) {             // ---------- GRU1 x-pass, t = s-1 ----------
      if (s >= 1 && s <= TT) {
        int t1 = s - 1;
        const float* xT   = h0T  + (size_t)(t1&1)*REC*Bsz;
        float*       xgwT = xg1T + (size_t)(t1&1)*G3*Bsz;
        float acc[24] = {0};
        gemm24s(xT, tid, wslice, acc);
        int b = tid, c0 = (blk - NB)*8;
        #pragma unroll
        for (int cl = 0; cl < 8; ++cl) {
          int c = c0 + cl;
          xgwT[(size_t)c*Bsz + b]         = acc[cl];
          xgwT[(size_t)(REC+c)*Bsz + b]   = acc[8+cl];
          xgwT[(size_t)(2*REC+c)*Bsz + b] = acc[16+cl];
        }
      }
    } else if (stage == 2) {             // ---------- GRU1 h-pass, t = s-2 ----------
      if (s >= 2 && s <= TT+1) {
        int t2 = s - 2;
        const float* hprevT = h1T  + (size_t)((t2+1)&1)*REC*Bsz;
        float*       hnewT  = h1T  + (size_t)(t2&1)*REC*Bsz;
        const float* xgrT   = xg1T + (size_t)(t2&1)*G3*Bsz;
        float acc[24] = {0};
        gemm24s(hprevT, tid, wslice, acc);
        int b = tid, c0 = (blk - 2*NB)*8;
        #pragma unroll
        for (int cl = 0; cl < 8; ++cl) {
          int c = c0 + cl;
          float xrv = xgrT[(size_t)c*Bsz + b];
          float xzv = xgrT[(size_t)(REC+c)*Bsz + b];
          float xnv = xgrT[(size_t)(2*REC+c)*Bsz + b];
          float r = sigmoidf_(xrv + acc[cl]   + bih1[c]     + bhh1[c]);
          float z = sigmoidf_(xzv + acc[8+cl] + bih1[REC+c] + bhh1[REC+c]);
          float n = tanhf   (xnv + bih1[2*REC+c] + r*(acc[16+cl] + bhh1[2*REC+c]));
          hnewT[(size_t)c*Bsz + b] = (1.f-z)*n + z*hprevT[(size_t)c*Bsz + b];
        }
      }
    } else {                             // ---------- custom cell, t = s-3 ----------
      if (s >= 3) {
        int t3 = s - 3;
        int b0 = (blk - 3*NB) << 4;      // 16 items per block
        const float* xT = h1T + (size_t)(t3&1)*REC*Bsz;
        const float* hp = hc  + (size_t)((t3+1)&1)*Bsz*NC;
        float*       hn = hc  + (size_t)(t3&1)*Bsz*NC;
        // stage x rows from transposed slab: idx = [k][it], 16-lane segments
        for (int idx = tid; idx < 16*REC; idx += 512) {
          int k = idx >> 4, it = idx & 15;
          S.xs[it][k] = xT[(size_t)k*Bsz + b0 + it];
        }
        if (l < NC) {
          #pragma unroll
          for (int q = 0; q < 2; ++q) {
            int it = (w<<1) + q;
            S.hs[it][l] = hp[(size_t)(b0+it)*NC + l];
          }
        }
        __syncthreads();
        for (int q = 0; q < 2; ++q) {
          int it = (w<<1) + q;
          int b = b0 + it;
          float v = -1e30f, u = 0.f, hpc = 0.f;
          if (l < NC) {
            const float4* wr4 = (const float4*)(cWih + (size_t)l*REC);
            const float4* wz4 = (const float4*)(cWih + (size_t)(NC+l)*REC);
            const float4* wn4 = (const float4*)(cWih + (size_t)(2*NC+l)*REC);
            const float4* xs4 = (const float4*)(S.xs[it]);
            float xr=0.f, xz=0.f, xn=0.f;
            #pragma unroll 2
            for (int k4 = 0; k4 < REC/4; ++k4) {
              float4 xv = xs4[k4];
              float4 wa = wr4[k4], wb = wz4[k4], wc = wn4[k4];
              xr += wa.x*xv.x + wa.y*xv.y + wa.z*xv.z + wa.w*xv.w;
              xz += wb.x*xv.x + wb.y*xv.y + wb.z*xv.z + wb.w*xv.w;
              xn += wc.x*xv.x + wc.y*xv.y + wc.z*xv.z + wc.w*xv.w;
            }
            float hr=0.f, hz=0.f;
            for (int k = 0; k < NC; ++k) {
              float hv = S.hs[it][k];
              hr = fmaf(hv, cWhh[(size_t)l*NC + k], hr);
              hz = fmaf(hv, cWhh[(size_t)(NC+l)*NC + k], hz);
            }
            float r = sigmoidf_(xr + hr + cb[l]);
            u       = sigmoidf_(xz + hz + cb[NC+l]);
            hpc = S.hs[it][l];
            S.rh[it][l] = r * hpc;       // reference: (r*h) @ Whh_n.T
            v = xn;
          }
          __syncthreads();
          if (l < NC) {
            float hnn = 0.f;
            for (int k = 0; k < NC; ++k)
              hnn = fmaf(S.rh[it][k], cWhh[(size_t)(2*NC+l)*NC + k], hnn);
            v = v + hnn + cb[2*NC+l];
          }
          float m = v;
          #pragma unroll
          for (int o = 32; o; o >>= 1) m = fmaxf(m, __shfl_xor(m, o));
          float e = (l < NC) ? __expf(v - m) : 0.f;
          float ss = e;
          #pragma unroll
          for (int o = 32; o; o >>= 1) ss += __shfl_xor(ss, o);
          if (l < NC) {
            float h2 = (1.f - u)*(e/ss) + u*hpc;
            hn[(size_t)b*NC + l] = h2;
            out[((size_t)b*TT + t3)*NC + l] = h2;
          }
          __syncthreads();
        }
      }
    }
    gbar3(bar, xcd, cntx, nx, s);
  }
}

extern "C" void kernel_launch(void* const* d_in, const int* in_sizes, int n_in,
                              void* d_out, int out_size, void* d_ws, size_t ws_size,
                              hipStream_t stream) {
  const float* z_in  = (const float*)d_in[0];
  const float* W0    = (const float*)d_in[1];
  const float* b0    = (const float*)d_in[2];
  const float* g0    = (const float*)d_in[3];
  const float* beta0 = (const float*)d_in[4];
  const float* W1    = (const float*)d_in[5];
  const float* b1    = (const float*)d_in[6];
  const float* g1    = (const float*)d_in[7];
  const float* beta1 = (const float*)d_in[8];
  const float* Wih0  = (const float*)d_in[9];
  const float* Whh0  = (const float*)d_in[10];
  const float* bih0  = (const float*)d_in[11];
  const float* bhh0  = (const float*)d_in[12];
  const float* Wih1  = (const float*)d_in[13];
  const float* Whh1  = (const float*)d_in[14];
  const float* bih1  = (const float*)d_in[15];
  const float* bhh1  = (const float*)d_in[16];
  const float* cWih  = (const float*)d_in[17];
  const float* cWhh  = (const float*)d_in[18];
  const float* cbih  = (const float*)d_in[19];
  float* out = (float*)d_out;

  float* ws   = (float*)d_ws;
  int*   bar  = (int*)ws;                            // 1024 slots (zeroed)
  float* h0T  = ws   + 1024;                         // 2*REC*Bsz (zeroed)
  float* h1T  = h0T  + 2*(size_t)REC*Bsz;            // 2*REC*Bsz (zeroed)
  float* hcb  = h1T  + 2*(size_t)REC*Bsz;            // 2*Bsz*NC  (zeroed)
  float* xg1T = hcb  + 2*(size_t)Bsz*NC;             // 2*G3*Bsz
  float* xg0T = xg1T + 2*(size_t)G3*Bsz;             // G3*Bsz
  float* z1   = xg0T + (size_t)G3*Bsz;               // Bsz*HID
  float* z2   = z1   + (size_t)Bsz*HID;              // Bsz*HID
  float* Wt2  = z2   + (size_t)Bsz*HID;              // 3*NB*WSL = 8.6 MB

  size_t zero_floats = 1024 + 4*(size_t)REC*Bsz + 2*(size_t)Bsz*NC;
  hipMemsetAsync(ws, 0, zero_floats*sizeof(float), stream);

  dense_bn_kernel<<<Bsz, 256, 0, stream>>>(z_in, W0, b0, g0, beta0, z1);
  dense_bn_kernel<<<Bsz, 256, 0, stream>>>(z1,   W1, b1, g1, beta1, z2);
  xg0v2_kernel   <<<128, 256, 0, stream>>>(z2, Wih0, bih0, xg0T);
  wtrans_kernel  <<<3*NB, 256, 0, stream>>>(Whh0, Wih1, Whh1, Wt2);

  pers_kernel<<<NGRID, 512, 0, stream>>>(xg0T, h0T, h1T, xg1T, hcb, out,
                                         Wt2, bhh0, bih1, bhh1, cWih, cWhh, cbih, bar);
}

// Round 12
// 10915.148 us; speedup vs baseline: 2.6190x; 1.0072x over previous
//
#include <hip/hip_runtime.h>
#include <math.h>

#define Bsz 512
#define HID 196
#define REC 488
#define NC  35
#define TT  120
#define G3  1464
#define NSLOT 123          // 4-deep pipeline: s in [0,123)

#define KT   8
#define NCH  61            // 488 = 61*8
#define NB   61            // blocks per GEMM stage (8 cols x 3 gates each)
#define CELLB 32           // cell blocks (16 batch items each)
#define NGRID (3*NB + CELLB)   // 215 blocks, 512 thr: 1 block/CU, 8 waves/CU
#define WSL  (NCH*KT*24)   // 11712 floats = 46.8 KB per-block weight slice

// s_getreg immediate: id | (offset<<6) | ((size-1)<<11); HW_REG_XCC_ID id=20
#define HWREG_XCC_ID (20 | (0 << 6) | (31 << 11))

// LDS: only the cell blocks use it (GEMM weights ride the scalar pipe).
struct CellSmem { float xs[16][492]; float hs[16][36]; float rh[16][36]; };

__device__ __forceinline__ float sigmoidf_(float x) { return 1.0f / (1.0f + __expf(-x)); }

// ---- legacy full-fence grid barrier (used ONCE at init) ----
__device__ __forceinline__ void gbar(int* bar, int target) {
  __syncthreads();
  if (threadIdx.x == 0) {
    __builtin_amdgcn_fence(__ATOMIC_RELEASE, "agent");
    __hip_atomic_fetch_add(bar, 1, __ATOMIC_RELAXED, __HIP_MEMORY_SCOPE_AGENT);
    while (__hip_atomic_load(bar, __ATOMIC_RELAXED, __HIP_MEMORY_SCOPE_AGENT) < target)
      __builtin_amdgcn_s_sleep(2);
    __builtin_amdgcn_fence(__ATOMIC_ACQUIRE, "agent");
  }
  __syncthreads();
}

// ---- per-slot barrier: leader-only release AND leader-only L2 invalidate ----
// bar[0]              : root (one inc per XCD per slot)
// bar[32*(1+x)]       : per-XCD arrival counter (cumulative)
// bar[32*(18+x)]      : per-XCD "L2 invalidated for slot s" flag (cumulative)
// Release side (R3-proven): last arriver per XCD = leader; only it executes
// the agent release fence (waitcnt + buffer_wbl2) -> 8 wbl2 walks/slot.
// Acquire side (R7-proven): after root fires, all dirty data is in L3. Stale
// copies live in each XCD L2 (killed ONCE by the leader's agent-acquire
// fence: buffer_inv sc1) and each CU L1 (killed per-block by plain
// buffer_inv, L1-only). Non-leaders wait for the leader's inv_done flag
// before their L1 inv, so no read can be served from a stale L2.
__device__ __forceinline__ void gbar3(int* bar, int xcd, int cntx, int nx, int s) {
  __syncthreads();
  if (threadIdx.x == 0) {
    int* bar1 = bar + 32*(1 + xcd);
    int old = __hip_atomic_fetch_add(bar1, 1, __ATOMIC_RELAXED, __HIP_MEMORY_SCOPE_AGENT);
    const bool leader = (old == cntx*(s+1) - 1);   // last arriver on this XCD
    if (leader) {
      __builtin_amdgcn_fence(__ATOMIC_RELEASE, "agent");   // waitcnt + buffer_wbl2
      __hip_atomic_fetch_add(bar, 1, __ATOMIC_RELAXED, __HIP_MEMORY_SCOPE_AGENT);
    }
    while (__hip_atomic_load(bar, __ATOMIC_RELAXED, __HIP_MEMORY_SCOPE_AGENT) < nx*(s+1))
      __builtin_amdgcn_s_sleep(2);
    if (leader) {
      __builtin_amdgcn_fence(__ATOMIC_ACQUIRE, "agent");   // buffer_inv sc1: L1+L2
      __hip_atomic_fetch_add(bar + 32*(18 + xcd), 1, __ATOMIC_RELAXED, __HIP_MEMORY_SCOPE_AGENT);
    } else {
      while (__hip_atomic_load(bar + 32*(18 + xcd), __ATOMIC_RELAXED, __HIP_MEMORY_SCOPE_AGENT) < (s+1))
        __builtin_amdgcn_s_sleep(1);
      // L1-only invalidate (no sc1): our XCD L2 is already clean.
      asm volatile("buffer_inv\n\ts_waitcnt vmcnt(0)" ::: "memory");
    }
  }
  __syncthreads();
}

// ---- prologue: z = bn(X @ W.T + bias, g, beta) ----
__global__ void dense_bn_kernel(const float* __restrict__ X, const float* __restrict__ W,
                                const float* __restrict__ bias, const float* __restrict__ g,
                                const float* __restrict__ beta, float* __restrict__ Y) {
  __shared__ float xs[HID];
  int b = blockIdx.x;
  for (int k = threadIdx.x; k < HID; k += blockDim.x) xs[k] = X[(size_t)b*HID + k];
  __syncthreads();
  int j = threadIdx.x;
  if (j < HID) {
    const float4* wr = (const float4*)(W + (size_t)j*HID);
    float acc = 0.f;
    #pragma unroll 7
    for (int k4 = 0; k4 < HID/4; ++k4) {
      float4 w4 = wr[k4];
      acc += xs[4*k4+0]*w4.x + xs[4*k4+1]*w4.y + xs[4*k4+2]*w4.z + xs[4*k4+3]*w4.w;
    }
    float v = (acc + bias[j]) * 0.9995003746f;   // 1/sqrt(1+1e-3)
    Y[(size_t)b*HID + j] = g[j]*v + beta[j];
  }
}

// ---- prologue: xg0T[c][b] = (z @ Wih0.T + bih0)^T  (constant over T) ----
__global__ __launch_bounds__(256)
void xg0v2_kernel(const float* __restrict__ Z, const float* __restrict__ Wih,
                  const float* __restrict__ bih, float* __restrict__ XGT) {
  __shared__ float zs[HID*4];
  int b0 = blockIdx.x << 2;
  for (int idx = threadIdx.x; idx < HID*4; idx += 256) {
    int k = idx >> 2, i = idx & 3;
    zs[idx] = Z[(size_t)(b0+i)*HID + k];
  }
  __syncthreads();
  for (int c = threadIdx.x; c < G3; c += 256) {
    const float4* wr = (const float4*)(Wih + (size_t)c*HID);
    float a0=0.f,a1=0.f,a2=0.f,a3=0.f;
    for (int k4 = 0; k4 < HID/4; ++k4) {
      float4 w = wr[k4];
      const float* zp = zs + (k4<<4);
      a0=fmaf(w.x,zp[0],a0);  a1=fmaf(w.x,zp[1],a1);  a2=fmaf(w.x,zp[2],a2);  a3=fmaf(w.x,zp[3],a3);
      a0=fmaf(w.y,zp[4],a0);  a1=fmaf(w.y,zp[5],a1);  a2=fmaf(w.y,zp[6],a2);  a3=fmaf(w.y,zp[7],a3);
      a0=fmaf(w.z,zp[8],a0);  a1=fmaf(w.z,zp[9],a1);  a2=fmaf(w.z,zp[10],a2); a3=fmaf(w.z,zp[11],a3);
      a0=fmaf(w.w,zp[12],a0); a1=fmaf(w.w,zp[13],a1); a2=fmaf(w.w,zp[14],a2); a3=fmaf(w.w,zp[15],a3);
    }
    float bb = bih[c];
    XGT[(size_t)c*Bsz + b0+0] = a0 + bb;
    XGT[(size_t)c*Bsz + b0+1] = a1 + bb;
    XGT[(size_t)c*Bsz + b0+2] = a2 + bb;
    XGT[(size_t)c*Bsz + b0+3] = a3 + bb;
  }
}

// ---- prologue: per-block contiguous weight slices ----
// Wt2[(stage*NB + j)*WSL + ck*192 + k*24 + (g*8+cl)] = Wsrc[(g*REC + j*8 + cl)*REC + ck*8 + k]
__global__ __launch_bounds__(256)
void wtrans_kernel(const float* __restrict__ Whh0, const float* __restrict__ Wih1,
                   const float* __restrict__ Whh1, float* __restrict__ Wt2) {
  int blk = blockIdx.x;                  // 3*61
  int stage = blk / NB, j = blk - stage*NB;
  const float* Wsrc = (stage==0) ? Whh0 : (stage==1) ? Wih1 : Whh1;
  float* dst = Wt2 + (size_t)blk*WSL;
  for (int idx = threadIdx.x; idx < WSL; idx += 256) {
    int ck = idx / 192, rem = idx - ck*192;
    int k = rem / 24, r = rem - k*24;
    int g = r >> 3, cl = r & 7;
    dst[idx] = Wsrc[(size_t)(g*REC + j*8 + cl)*REC + ck*8 + k];
  }
}

// ---- acc[24] += AT[:,b] @ W-slice (24 colgates), K=488 ----
// AT layout [k][512]: per-k A-loads wave-coalesced; depth-1 chunk prefetch.
// W read via BLOCK-UNIFORM addresses from global -> compiler emits s_load
// (scalar cache + SGPR operand in v_fma): zero LDS traffic in the K-loop.
__device__ __forceinline__ void gemm24s(const float* __restrict__ AT, int b,
                                        const float* __restrict__ wp,
                                        float (&acc)[24])
{
  float av[KT], nv[KT];
  #pragma unroll
  for (int k = 0; k < KT; ++k) av[k] = AT[(size_t)k*Bsz + b];
  for (int ck = 0; ck < NCH; ++ck) {
    if (ck + 1 < NCH) {
      const float* src = AT + (size_t)(ck+1)*KT*Bsz + b;
      #pragma unroll
      for (int k = 0; k < KT; ++k) nv[k] = src[(size_t)k*Bsz];
    }
    const float* w = wp + ck*192;        // block-uniform -> scalar loads
    #pragma unroll
    for (int k = 0; k < KT; ++k) {
      float a = av[k];
      #pragma unroll
      for (int r = 0; r < 24; ++r)
        acc[r] = fmaf(a, w[k*24 + r], acc[r]);
    }
    #pragma unroll
    for (int k = 0; k < KT; ++k) av[k] = nv[k];
  }
}

// ---- persistent kernel: 4-stage time pipeline, 215 blocks x 512 threads ----
// [0,61): GRU0 t=s | [61,122): GRU1 x-pass t=s-1 | [122,183): GRU1 h-pass t=s-2
// | [183,215): cell t=s-3.  Recurrent states TRANSPOSED [c][b]; hc normal.
__global__ __launch_bounds__(512)
void pers_kernel(const float* __restrict__ xg0T,
                 float* __restrict__ h0T, float* __restrict__ h1T,
                 float* __restrict__ xg1T, float* __restrict__ hc,
                 float* __restrict__ out,
                 const float* __restrict__ Wt2,
                 const float* __restrict__ bhh0,
                 const float* __restrict__ bih1, const float* __restrict__ bhh1,
                 const float* __restrict__ cWih, const float* __restrict__ cWhh,
                 const float* __restrict__ cb, int* __restrict__ bar)
{
  __shared__ CellSmem S;
  const int blk = blockIdx.x;
  const int tid = threadIdx.x;
  const int stage = (blk < NB) ? 0 : (blk < 2*NB) ? 1 : (blk < 3*NB) ? 2 : 3;
  const int l = tid & 63, w = tid >> 6;
  const float* wslice = Wt2 + (size_t)blk*WSL;   // block-uniform base

  // ---- init: census of blocks per XCD (true residency via XCC_ID) ----
  const int xcd = __builtin_amdgcn_s_getreg(HWREG_XCC_ID) & 7;
  if (tid == 0)
    __hip_atomic_fetch_add(bar + 32*(9 + xcd), 1, __ATOMIC_RELAXED, __HIP_MEMORY_SCOPE_AGENT);
  gbar(bar + 544, NGRID);              // full-fence barrier: census stable
  int cntx = 0, nx = 0;
  if (tid == 0) {
    cntx = __hip_atomic_load(bar + 32*(9 + xcd), __ATOMIC_RELAXED, __HIP_MEMORY_SCOPE_AGENT);
    #pragma unroll
    for (int x = 0; x < 8; ++x)
      nx += (__hip_atomic_load(bar + 32*(9 + x), __ATOMIC_RELAXED, __HIP_MEMORY_SCOPE_AGENT) > 0);
  }

  for (int s = 0; s < NSLOT; ++s) {
    if (stage == 0) {                    // ---------- GRU0, t = s ----------
      if (s < TT) {
        int j = blk;
        const float* hprevT = h0T + (size_t)((s+1)&1)*REC*Bsz;
        float*       hnewT  = h0T + (size_t)(s&1)*REC*Bsz;
        float acc[24] = {0};
        gemm24s(hprevT, tid, wslice, acc);
        int b = tid, c0 = j*8;
        #pragma unroll
        for (int cl = 0; cl < 8; ++cl) {
          int c = c0 + cl;
          float xrv = xg0T[(size_t)c*Bsz + b];
          float xzv = xg0T[(size_t)(REC+c)*Bsz + b];
          float xnv = xg0T[(size_t)(2*REC+c)*Bsz + b];
          float r = sigmoidf_(xrv + acc[cl]      + bhh0[c]);
          float z = sigmoidf_(xzv + acc[8+cl]    + bhh0[REC+c]);
          float n = tanhf   (xnv + r*(acc[16+cl] + bhh0[2*REC+c]));
          hnewT[(size_t)c*Bsz + b] = (1.f-z)*n + z*hprevT[(size_t)c*Bsz + b];
        }
      }
    } else if (stage == 1) {             // ---------- GRU1 x-pass, t = s-1 ----------
      if (s >= 1 && s <= TT) {
        int t1 = s - 1;
        const float* xT   = h0T  + (size_t)(t1&1)*REC*Bsz;
        float*       xgwT = xg1T + (size_t)(t1&1)*G3*Bsz;
        float acc[24] = {0};
        gemm24s(xT, tid, wslice, acc);
        int b = tid, c0 = (blk - NB)*8;
        #pragma unroll
        for (int cl = 0; cl < 8; ++cl) {
          int c = c0 + cl;
          xgwT[(size_t)c*Bsz + b]         = acc[cl];
          xgwT[(size_t)(REC+c)*Bsz + b]   = acc[8+cl];
          xgwT[(size_t)(2*REC+c)*Bsz + b] = acc[16+cl];
        }
      }
    } else if (stage == 2) {             // ---------- GRU1 h-pass, t = s-2 ----------
      if (s >= 2 && s <= TT+1) {
        int t2 = s - 2;
        const float* hprevT = h1T  + (size_t)((t2+1)&1)*REC*Bsz;
        float*       hnewT  = h1T  + (size_t)(t2&1)*REC*Bsz;
        const float* xgrT   = xg1T + (size_t)(t2&1)*G3*Bsz;
        float acc[24] = {0};
        gemm24s(hprevT, tid, wslice, acc);
        int b = tid, c0 = (blk - 2*NB)*8;
        #pragma unroll
        for (int cl = 0; cl < 8; ++cl) {
          int c = c0 + cl;
          float xrv = xgrT[(size_t)c*Bsz + b];
          float xzv = xgrT[(size_t)(REC+c)*Bsz + b];
          float xnv = xgrT[(size_t)(2*REC+c)*Bsz + b];
          float r = sigmoidf_(xrv + acc[cl]   + bih1[c]     + bhh1[c]);
          float z = sigmoidf_(xzv + acc[8+cl] + bih1[REC+c] + bhh1[REC+c]);
          float n = tanhf   (xnv + bih1[2*REC+c] + r*(acc[16+cl] + bhh1[2*REC+c]));
          hnewT[(size_t)c*Bsz + b] = (1.f-z)*n + z*hprevT[(size_t)c*Bsz + b];
        }
      }
    } else {                             // ---------- custom cell, t = s-3 ----------
      if (s >= 3) {
        int t3 = s - 3;
        int b0 = (blk - 3*NB) << 4;      // 16 items per block
        const float* xT = h1T + (size_t)(t3&1)*REC*Bsz;
        const float* hp = hc  + (size_t)((t3+1)&1)*Bsz*NC;
        float*       hn = hc  + (size_t)(t3&1)*Bsz*NC;
        // stage x rows from transposed slab: idx = [k][it], 16-lane segments
        for (int idx = tid; idx < 16*REC; idx += 512) {
          int k = idx >> 4, it = idx & 15;
          S.xs[it][k] = xT[(size_t)k*Bsz + b0 + it];
        }
        if (l < NC) {
          #pragma unroll
          for (int q = 0; q < 2; ++q) {
            int it = (w<<1) + q;
            S.hs[it][l] = hp[(size_t)(b0+it)*NC + l];
          }
        }
        __syncthreads();
        for (int q = 0; q < 2; ++q) {
          int it = (w<<1) + q;
          int b = b0 + it;
          float v = -1e30f, u = 0.f, hpc = 0.f;
          if (l < NC) {
            const float4* wr4 = (const float4*)(cWih + (size_t)l*REC);
            const float4* wz4 = (const float4*)(cWih + (size_t)(NC+l)*REC);
            const float4* wn4 = (const float4*)(cWih + (size_t)(2*NC+l)*REC);
            const float4* xs4 = (const float4*)(S.xs[it]);
            float xr=0.f, xz=0.f, xn=0.f;
            #pragma unroll 2
            for (int k4 = 0; k4 < REC/4; ++k4) {
              float4 xv = xs4[k4];
              float4 wa = wr4[k4], wb = wz4[k4], wc = wn4[k4];
              xr += wa.x*xv.x + wa.y*xv.y + wa.z*xv.z + wa.w*xv.w;
              xz += wb.x*xv.x + wb.y*xv.y + wb.z*xv.z + wb.w*xv.w;
              xn += wc.x*xv.x + wc.y*xv.y + wc.z*xv.z + wc.w*xv.w;
            }
            float hr=0.f, hz=0.f;
            for (int k = 0; k < NC; ++k) {
              float hv = S.hs[it][k];
              hr = fmaf(hv, cWhh[(size_t)l*NC + k], hr);
              hz = fmaf(hv, cWhh[(size_t)(NC+l)*NC + k], hz);
            }
            float r = sigmoidf_(xr + hr + cb[l]);
            u       = sigmoidf_(xz + hz + cb[NC+l]);
            hpc = S.hs[it][l];
            S.rh[it][l] = r * hpc;       // reference: (r*h) @ Whh_n.T
            v = xn;
          }
          __syncthreads();
          if (l < NC) {
            float hnn = 0.f;
            for (int k = 0; k < NC; ++k)
              hnn = fmaf(S.rh[it][k], cWhh[(size_t)(2*NC+l)*NC + k], hnn);
            v = v + hnn + cb[2*NC+l];
          }
          float m = v;
          #pragma unroll
          for (int o = 32; o; o >>= 1) m = fmaxf(m, __shfl_xor(m, o));
          float e = (l < NC) ? __expf(v - m) : 0.f;
          float ss = e;
          #pragma unroll
          for (int o = 32; o; o >>= 1) ss += __shfl_xor(ss, o);
          if (l < NC) {
            float h2 = (1.f - u)*(e/ss) + u*hpc;
            hn[(size_t)b*NC + l] = h2;
            out[((size_t)b*TT + t3)*NC + l] = h2;
          }
          __syncthreads();
        }
      }
    }
    gbar3(bar, xcd, cntx, nx, s);
  }
}

extern "C" void kernel_launch(void* const* d_in, const int* in_sizes, int n_in,
                              void* d_out, int out_size, void* d_ws, size_t ws_size,
                              hipStream_t stream) {
  const float* z_in  = (const float*)d_in[0];
  const float* W0    = (const float*)d_in[1];
  const float* b0    = (const float*)d_in[2];
  const float* g0    = (const float*)d_in[3];
  const float* beta0 = (const float*)d_in[4];
  const float* W1    = (const float*)d_in[5];
  const float* b1    = (const float*)d_in[6];
  const float* g1    = (const float*)d_in[7];
  const float* beta1 = (const float*)d_in[8];
  const float* Wih0  = (const float*)d_in[9];
  const float* Whh0  = (const float*)d_in[10];
  const float* bih0  = (const float*)d_in[11];
  const float* bhh0  = (const float*)d_in[12];
  const float* Wih1  = (const float*)d_in[13];
  const float* Whh1  = (const float*)d_in[14];
  const float* bih1  = (const float*)d_in[15];
  const float* bhh1  = (const float*)d_in[16];
  const float* cWih  = (const float*)d_in[17];
  const float* cWhh  = (const float*)d_in[18];
  const float* cbih  = (const float*)d_in[19];
  float* out = (float*)d_out;

  float* ws   = (float*)d_ws;
  int*   bar  = (int*)ws;                            // 1024 slots (zeroed)
  float* h0T  = ws   + 1024;                         // 2*REC*Bsz (zeroed)
  float* h1T  = h0T  + 2*(size_t)REC*Bsz;            // 2*REC*Bsz (zeroed)
  float* hcb  = h1T  + 2*(size_t)REC*Bsz;            // 2*Bsz*NC  (zeroed)
  float* xg1T = hcb  + 2*(size_t)Bsz*NC;             // 2*G3*Bsz
  float* xg0T = xg1T + 2*(size_t)G3*Bsz;             // G3*Bsz
  float* z1   = xg0T + (size_t)G3*Bsz;               // Bsz*HID
  float* z2   = z1   + (size_t)Bsz*HID;              // Bsz*HID
  float* Wt2  = z2   + (size_t)Bsz*HID;              // 3*NB*WSL = 8.6 MB

  size_t zero_floats = 1024 + 4*(size_t)REC*Bsz + 2*(size_t)Bsz*NC;
  (void)hipMemsetAsync(ws, 0, zero_floats*sizeof(float), stream);

  dense_bn_kernel<<<Bsz, 256, 0, stream>>>(z_in, W0, b0, g0, beta0, z1);
  dense_bn_kernel<<<Bsz, 256, 0, stream>>>(z1,   W1, b1, g1, beta1, z2);
  xg0v2_kernel   <<<128, 256, 0, stream>>>(z2, Wih0, bih0, xg0T);
  wtrans_kernel  <<<3*NB, 256, 0, stream>>>(Whh0, Wih1, Whh1, Wt2);

  pers_kernel<<<NGRID, 512, 0, stream>>>(xg0T, h0T, h1T, xg1T, hcb, out,
                                         Wt2, bhh0, bih1, bhh1, cWih, cWhh, cbih, bar);
}